// Round 11
// baseline (526.004 us; speedup 1.0000x reference)
//
#include <hip/hip_runtime.h>
#include <stdint.h>

typedef unsigned int uint;
typedef unsigned short ushort;
typedef __attribute__((ext_vector_type(8))) short short8;
typedef __attribute__((ext_vector_type(4))) float f32x4;

__device__ __forceinline__ uint f2bf(float f) {
  uint u = __float_as_uint(f);
  return (u + 0x7fffu + ((u >> 16) & 1u)) >> 16;
}
__device__ __forceinline__ float bf2f(uint us) {
  return __uint_as_float(us << 16);
}

// ---------------- weight preprocessing ----------------
// w1: (256, 128, 1, 11)  w2: (256, 128, 1, 40)
// wp1 (bf16): [t(11)][c(256)][d(64)] = w1[c][64+d][t]; then U block at
//   180224 + c*64 + d = sum_t (w1[c][d][t] - w1[c][64+d][t])
// wpack (bf16): conv2 GEMM B, layout [kb(61)][c(256)][kk(64)]; K order:
//   k<64:        U2[d=k][c]
//   64<=k<1344:  j-major neighbor: j=(k-64)>>6, d=(k-64)&63 -> w2[c][64+d][j]
//   1344<=k<3904: interleave: q=k-1344=ci*20+jj -> w2[c][ci][20+jj]
__global__ __launch_bounds__(256) void prep_weights(
    const float* __restrict__ w1, const float* __restrict__ w2,
    ushort* __restrict__ wp1, ushort* __restrict__ wpack) {
  int g = blockIdx.x * 256 + threadIdx.x;
  if (g < 180224) {
    int t = g >> 14;
    int r = g & 16383;
    int c = r >> 6, d = r & 63;
    wp1[g] = (ushort)f2bf(w1[c * 1408 + (64 + d) * 11 + t]);
  } else if (g < 196608) {
    int q = g - 180224;
    int c = q >> 6, d = q & 63;
    float s = 0.f;
    for (int t = 0; t < 11; ++t)
      s += w1[c * 1408 + d * 11 + t] - w1[c * 1408 + (64 + d) * 11 + t];
    wp1[g] = (ushort)f2bf(s);
  } else {
    int gp = g - 196608;            // < 999424 = 61*16384
    int kb = gp >> 14;
    int r = gp & 16383;
    int c = r >> 6, kk = r & 63;
    int k = kb * 64 + kk;
    float val;
    if (k < 64) {
      int d = k;
      float s = 0.f;
      for (int j = 0; j < 20; ++j)
        s += w2[c * 5120 + d * 40 + j] - w2[c * 5120 + (64 + d) * 40 + j];
      val = s;
    } else if (k < 1344) {
      int q = k - 64; int j = q >> 6, d = q & 63;
      val = w2[c * 5120 + (64 + d) * 40 + j];
    } else {
      int q = k - 1344; int ci = q / 20, jj = q - ci * 20;
      val = w2[c * 5120 + ci * 40 + 20 + jj];
    }
    wpack[gp] = (ushort)f2bf(val);
  }
}

// ---------------- x transpose: bf16 [b][n][d] + fp32 [b][n][d] ----------------
__global__ __launch_bounds__(256) void transpose_x(const float* __restrict__ x,
                                                   uint* __restrict__ xtu,
                                                   float* __restrict__ xtf) {
  __shared__ float t[64][65];
  int tid = threadIdx.x;
  int blk = blockIdx.x;            // 256 = 8 b x 32 n-tiles
  int b = blk >> 5, n0 = (blk & 31) << 6;
  const float* xb = x + b * 131072;
  #pragma unroll
  for (int it = 0; it < 16; ++it) {
    int d = (it << 2) + (tid >> 6);
    int n = tid & 63;
    t[d][n] = xb[d * 2048 + n0 + n];
  }
  __syncthreads();
  #pragma unroll
  for (int it = 0; it < 8; ++it) {
    int n = (it << 3) + (tid >> 5);
    int dp = tid & 31;
    float f0 = t[2 * dp][n], f1 = t[2 * dp + 1][n];
    uint v = f2bf(f0) | (f2bf(f1) << 16);
    size_t col = (size_t)(b * 2048 + n0 + n);
    xtu[col * 32 + dp] = v;
    float2 fv; fv.x = f0; fv.y = f1;
    *(float2*)&xtf[(col << 6) + 2 * dp] = fv;
  }
}

// ---------------- squared norms (fp32, for the pre-selection only) ----------------
__global__ __launch_bounds__(256) void sqnorm_kernel(const float* __restrict__ x,
                                                     float* __restrict__ sqf) {
  int g = blockIdx.x * 256 + threadIdx.x;  // 16384
  int b = g >> 11, n = g & 2047;
  const float* xp = x + b * 131072 + n;
  float s = 0.f;
  #pragma unroll
  for (int d = 0; d < 64; ++d) { float v = xp[d * 2048]; s += v * v; }
  sqf[g] = s;
}

// ---------------- kNN v6: MFMA dists -> packed-u32 keys, min-only tournament,
// ---------------- fp64 exact re-rank of the top-31 superset ----------------
__global__ __launch_bounds__(1024) void knn_kernel(
    const float* __restrict__ xtf, const ushort* __restrict__ xbf_t,
    const float* __restrict__ sqf, int* __restrict__ idxout) {
  __shared__ uint dist[16][2048];   // 128 KB packed keys
  __shared__ int cand[16][31];
  __shared__ double dkey[16][31];
  int tid = threadIdx.x;
  int wv = tid >> 6, lane = tid & 63;
  int row0 = blockIdx.x << 4;
  int b = row0 >> 11, n0 = row0 & 2047;
  const ushort* xt = xbf_t + ((size_t)b << 17);
  const float* sqb = sqf + (b << 11);
  int m = lane & 15, quad = lane >> 4;
  short8 afr0 = *(const short8*)(xt + ((size_t)(n0 + m) << 6) + quad * 8);
  short8 afr1 = *(const short8*)(xt + ((size_t)(n0 + m) << 6) + 32 + quad * 8);
  // phase 1: wave wv computes col-tiles [wv*8, wv*8+8); writes packed keys
  for (int t = 0; t < 8; ++t) {
    int col = (((wv << 3) + t) << 4) + m;
    short8 bfr0 = *(const short8*)(xt + ((size_t)col << 6) + quad * 8);
    short8 bfr1 = *(const short8*)(xt + ((size_t)col << 6) + 32 + quad * 8);
    f32x4 c = {};
    c = __builtin_amdgcn_mfma_f32_16x16x32_bf16(afr0, bfr0, c, 0, 0, 0);
    c = __builtin_amdgcn_mfma_f32_16x16x32_bf16(afr1, bfr1, c, 0, 0, 0);
    float sq = sqb[col];
    #pragma unroll
    for (int r = 0; r < 4; ++r) {
      float f = sq - 2.f * c[r];
      uint u = __float_as_uint(f);
      uint srt = u ^ ((uint)((int)u >> 31) | 0x80000000u);
      dist[quad * 4 + r][col] = (srt & 0xFFFFF800u) | (uint)col;
    }
  }
  __syncthreads();
  uint* dr = dist[wv];
  int selfcol = n0 + wv;
  if ((selfcol & 63) == lane) dr[selfcol] = 0xFFFFFFFFu;  // kill self (own strip)
  // per-lane sorted top-4 over strip col = (l<<6)+lane
  uint v0, v1, v2, v3;
  auto scan4 = [&]() {
    v0 = v1 = v2 = v3 = 0xFFFFFFFFu;
    #pragma unroll
    for (int l = 0; l < 32; ++l) {
      uint v = dr[(l << 6) + lane];
      uint t0 = v0 > v ? v0 : v;   v0 = v0 < v ? v0 : v;
      uint t1 = v1 > t0 ? v1 : t0; v1 = v1 < t0 ? v1 : t0;
      uint t2 = v2 > t1 ? v2 : t1; v2 = v2 < t1 ? v2 : t1;
      v3 = v3 < t2 ? v3 : t2;
    }
  };
  scan4();
  for (int pick = 0; pick < 31; ++pick) {
    uint bv = v0;
    #pragma unroll
    for (int off = 32; off > 0; off >>= 1) {
      uint ov = (uint)__shfl_xor((int)bv, off);
      bv = bv < ov ? bv : ov;
    }
    int bj = (int)(bv & 2047u);
    if (lane == 0) cand[wv][pick] = bj;
    if ((bj & 63) == lane) {
      dr[bj] = 0xFFFFFFFFu;
      v0 = v1; v1 = v2; v2 = v3; v3 = 0xFFFFFFFFu;
      if (v0 == 0xFFFFFFFFu) scan4();   // ~never (4th win of one lane)
    }
  }
  __syncthreads();
  // phase 3: exact fp64 keys from fp32 xtf (contiguous 256-B columns)
  const float* xc = xtf + ((size_t)b << 17);
  const float4* xi4 = (const float4*)(xc + ((size_t)selfcol << 6));
  if (lane < 31) {
    int c = cand[wv][lane];
    const float4* xj4 = (const float4*)(xc + ((size_t)c << 6));
    double dt = 0.0, s2 = 0.0;
    #pragma unroll 4
    for (int d4 = 0; d4 < 16; ++d4) {
      float4 vj = xj4[d4];
      float4 vi = xi4[d4];
      double a0 = (double)vj.x, a1 = (double)vj.y, a2 = (double)vj.z, a3 = (double)vj.w;
      s2 += a0 * a0 + a1 * a1 + a2 * a2 + a3 * a3;
      dt += (double)vi.x * a0 + (double)vi.y * a1 + (double)vi.z * a2 + (double)vi.w * a3;
    }
    dkey[wv][lane] = s2 - 2.0 * dt;
  }
  __syncthreads();
  if (lane < 31) {
    double kl = dkey[wv][lane];
    int ci = cand[wv][lane];
    int rank = 0;
    for (int mm = 0; mm < 31; ++mm) {
      double km = dkey[wv][mm];
      int cm = cand[wv][mm];
      if (km < kl || (km == kl && cm < ci)) ++rank;
    }
    if (rank < 20) idxout[(row0 + wv) * 20 + rank] = ci;
  }
}

// ---------------- conv1 as bf16 MFMA (tap decomposition, xT staging) ----------------
__global__ __launch_bounds__(256) void conv1_mfma(
    const ushort* __restrict__ xbf_t, const int* __restrict__ idxbuf,
    const ushort* __restrict__ wp1, uint* __restrict__ hu) {
  __shared__ ushort sl[21][16][72];   // 48384 B; rows 144 B (16-B aligned)
  __shared__ int nidx[16][20];
  int tid = threadIdx.x;
  int pg = blockIdx.x >> 1;
  int cg = blockIdx.x & 1;
  int p0 = pg << 4;
  int b = p0 >> 11, n0 = p0 & 2047;
  const ushort* xt = xbf_t + ((size_t)b << 17);
  for (int v = tid; v < 320; v += 256) {
    int p = v / 20, j = v - p * 20;
    nidx[p][j] = idxbuf[(p0 + p) * 20 + j];
  }
  __syncthreads();
  // 21 slices x 16 points x 8 chunks of short8
  for (int v = tid; v < 2688; v += 256) {
    int s = v >> 7;
    int r = v & 127;
    int p = r >> 3, i = r & 7;
    int col = (s == 0) ? (n0 + p) : nidx[p][s - 1];
    *(short8*)&sl[s][p][i << 3] =
        *(const short8*)(xt + ((size_t)col << 6) + (i << 3));
  }
  __syncthreads();
  int lane = tid & 63, wave = tid >> 6;
  int m = lane & 15, quad = lane >> 4;
  int ch0 = (cg << 7) + (wave << 4) + m;    // + ct*64
  f32x4 acc[10][2] = {};
  f32x4 cacc[2] = {};
  {
    short8 a0 = *(const short8*)&sl[0][m][quad * 8];
    short8 a1 = *(const short8*)&sl[0][m][32 + quad * 8];
    #pragma unroll
    for (int ct = 0; ct < 2; ++ct) {
      const ushort* urow = wp1 + 180224 + (ch0 + ct * 64) * 64 + quad * 8;
      short8 b0 = *(const short8*)(urow);
      short8 b1 = *(const short8*)(urow + 32);
      cacc[ct] = __builtin_amdgcn_mfma_f32_16x16x32_bf16(a0, b0, cacc[ct], 0, 0, 0);
      cacc[ct] = __builtin_amdgcn_mfma_f32_16x16x32_bf16(a1, b1, cacc[ct], 0, 0, 0);
    }
  }
  #pragma unroll
  for (int t = 0; t < 11; ++t) {
    short8 b0[2], b1[2];
    #pragma unroll
    for (int ct = 0; ct < 2; ++ct) {
      const ushort* brow = wp1 + t * 16384 + (ch0 + ct * 64) * 64 + quad * 8;
      b0[ct] = *(const short8*)(brow);
      b1[ct] = *(const short8*)(brow + 32);
    }
    #pragma unroll
    for (int ko = 0; ko < 10; ++ko) {
      int s = 1 + ko + t;
      short8 a0 = *(const short8*)&sl[s][m][quad * 8];
      short8 a1 = *(const short8*)&sl[s][m][32 + quad * 8];
      #pragma unroll
      for (int ct = 0; ct < 2; ++ct) {
        acc[ko][ct] = __builtin_amdgcn_mfma_f32_16x16x32_bf16(a0, b0[ct], acc[ko][ct], 0, 0, 0);
        acc[ko][ct] = __builtin_amdgcn_mfma_f32_16x16x32_bf16(a1, b1[ct], acc[ko][ct], 0, 0, 0);
      }
    }
  }
  // epilogue: D layout col=lane&15 -> channel, row=quad*4+r -> point
  #pragma unroll
  for (int ct = 0; ct < 2; ++ct) {
    int c = ch0 + ct * 64;
    #pragma unroll
    for (int r = 0; r < 4; ++r) {
      int p = (quad << 2) + r;
      int base5 = ((p0 + p) * 256 + c) * 5;
      float cc = cacc[ct][r];
      #pragma unroll
      for (int q = 0; q < 5; ++q) {
        float f0 = acc[2 * q][ct][r] + cc;
        float f1 = acc[2 * q + 1][ct][r] + cc;
        hu[base5 + q] = f2bf(f0) | (f2bf(f1) << 16);
      }
    }
  }
}

// ---------------- BN stats ----------------
__global__ __launch_bounds__(256) void stats1_kernel(const uint* __restrict__ hu,
                                                     float* __restrict__ stats) {
  int c = threadIdx.x;
  float s = 0.f, ss = 0.f;
  for (int row = blockIdx.x; row < 16384; row += 1024) {
    int base = (row * 256 + c) * 5;
    #pragma unroll
    for (int q = 0; q < 5; ++q) {
      uint v = hu[base + q];
      float f0 = bf2f(v & 0xffffu), f1 = bf2f(v >> 16);
      s += f0 + f1; ss += f0 * f0 + f1 * f1;
    }
  }
  atomicAdd(&stats[c], s);
  atomicAdd(&stats[256 + c], ss);
}

__global__ void finalize_kernel(const float* __restrict__ stats,
                                const float* __restrict__ gamma,
                                const float* __restrict__ beta,
                                float* __restrict__ coef, float inv_count) {
  int c = threadIdx.x;
  float m = stats[c] * inv_count;
  float var = stats[256 + c] * inv_count - m * m;
  float a = gamma[c] * rsqrtf(var + 1e-5f);
  coef[c] = a;
  coef[256 + c] = beta[c] - m * a;
}

// ---------------- conv2 as bf16 MFMA GEMM, 4-kb chunked double-buffered
// staging: per phase each thread issues 4 independent 16-B loads (hoisted
// before transforms), one barrier per phase (16 total vs 61). Block = 32 pts
// x 256 ch, 512 blocks. ----------------
__global__ __launch_bounds__(256) void conv2_mfma(
    const ushort* __restrict__ xbf_t, const int* __restrict__ idxbuf,
    const uint* __restrict__ hu, const float* __restrict__ coef1,
    const ushort* __restrict__ wpack, float* __restrict__ yraw) {
  __shared__ ushort As[2][4][32][72];   // 36864 B
  __shared__ int nidx[32][20];
  __shared__ float cf[512];
  int tid = threadIdx.x;
  int p0 = blockIdx.x << 5;          // 32 points per block
  int b = p0 >> 11, n0 = p0 & 2047;
  const ushort* xt = xbf_t + ((size_t)b << 17);

  cf[tid] = coef1[tid];
  cf[256 + tid] = coef1[256 + tid];
  for (int v = tid; v < 640; v += 256) {
    int p = v / 20, j = v - p * 20;
    nidx[p][j] = idxbuf[(p0 + p) * 20 + j];
  }
  __syncthreads();

  int pp = tid >> 3;                 // point 0..31
  int ii = tid & 7;                  // 8-col chunk within 64
  int off = ii << 3;

  // stage kbs [phase*4, phase*4+4) ∩ [0,61): loads first, then transforms
  auto build = [&](int phase, int buf) {
    int kb0 = phase << 2;
    short8 xv[4];
    uint4 hv[4];
    #pragma unroll
    for (int kc = 0; kc < 4; ++kc) {
      int kb = kb0 + kc;
      if (kb >= 61) continue;
      if (kb < 21) {
        int col = (kb == 0) ? (n0 + pp) : nidx[pp][kb - 1];
        xv[kc] = *(const short8*)(xt + ((size_t)col << 6) + off);
      } else {
        int q0 = (kb - 21) * 64 + off;
        hv[kc] = *(const uint4*)(hu + (size_t)(p0 + pp) * 1280 + (q0 >> 1));
      }
    }
    #pragma unroll
    for (int kc = 0; kc < 4; ++kc) {
      int kb = kb0 + kc;
      if (kb >= 61) continue;
      if (kb < 21) {
        *(short8*)&As[buf][kc][pp][off] = xv[kc];
      } else {
        int q0 = (kb - 21) * 64 + off;
        uint4 hvv = hv[kc];
        float f[8];
        f[0] = bf2f(hvv.x & 0xffffu); f[1] = bf2f(hvv.x >> 16);
        f[2] = bf2f(hvv.y & 0xffffu); f[3] = bf2f(hvv.y >> 16);
        f[4] = bf2f(hvv.z & 0xffffu); f[5] = bf2f(hvv.z >> 16);
        f[6] = bf2f(hvv.w & 0xffffu); f[7] = bf2f(hvv.w >> 16);
        ushort o[8];
        #pragma unroll
        for (int i = 0; i < 8; ++i) {
          int ch = (q0 + i) / 10;
          float vv = f[i] * cf[ch] + cf[256 + ch];
          vv = vv > 0.f ? vv : 0.01f * vv;
          o[i] = (ushort)f2bf(vv);
        }
        *(short8*)&As[buf][kc][pp][off] = *(short8*)o;
      }
    }
  };

  int lane = tid & 63, wave = tid >> 6;
  int m = lane & 15, quad = lane >> 4;
  int n0w = wave << 6;
  f32x4 acc[2][4] = {};

  build(0, 0);
  __syncthreads();
  for (int phase = 0; phase < 16; ++phase) {
    int buf = phase & 1;
    if (phase < 15) build(phase + 1, buf ^ 1);
    #pragma unroll
    for (int kc = 0; kc < 4; ++kc) {
      int kb = (phase << 2) + kc;
      if (kb >= 61) break;
      #pragma unroll
      for (int ks = 0; ks < 2; ++ks) {
        short8 afr0 = *(const short8*)&As[buf][kc][m][ks * 32 + quad * 8];
        short8 afr1 = *(const short8*)&As[buf][kc][16 + m][ks * 32 + quad * 8];
        #pragma unroll
        for (int nt = 0; nt < 4; ++nt) {
          const ushort* bp = wpack + (((size_t)kb << 14) |
                                      (uint)((n0w + nt * 16 + m) << 6) |
                                      (uint)(ks * 32 + quad * 8));
          short8 bfr = *(const short8*)bp;
          acc[0][nt] = __builtin_amdgcn_mfma_f32_16x16x32_bf16(afr0, bfr, acc[0][nt], 0, 0, 0);
          acc[1][nt] = __builtin_amdgcn_mfma_f32_16x16x32_bf16(afr1, bfr, acc[1][nt], 0, 0, 0);
        }
      }
    }
    __syncthreads();
  }
  #pragma unroll
  for (int mt = 0; mt < 2; ++mt) {
    #pragma unroll
    for (int nt = 0; nt < 4; ++nt) {
      int col = n0w + nt * 16 + m;
      #pragma unroll
      for (int r = 0; r < 4; ++r) {
        int prow = mt * 16 + quad * 4 + r;
        yraw[(size_t)(p0 + prow) * 256 + col] = acc[mt][nt][r];
      }
    }
  }
}

__global__ __launch_bounds__(256) void stats2_kernel(const float* __restrict__ yraw,
                                                     float* __restrict__ stats) {
  int c = threadIdx.x;
  float s = 0.f, ss = 0.f;
  for (int row = blockIdx.x; row < 16384; row += 1024) {
    float v = yraw[row * 256 + c];
    s += v; ss += v * v;
  }
  atomicAdd(&stats[c], s);
  atomicAdd(&stats[256 + c], ss);
}

// ---------------- BN2 + relu + transpose to (b, c, n) ----------------
__global__ __launch_bounds__(256) void out_kernel(const float* __restrict__ yraw,
                                                  const float* __restrict__ coef2,
                                                  float* __restrict__ out) {
  __shared__ float t[64][257];
  int tid = threadIdx.x;
  int blk = blockIdx.x;            // 256 = 8 b x 32 n-tiles
  int b = blk >> 5, n0 = (blk & 31) << 6;
  for (int it = 0; it < 64; ++it)
    t[it][tid] = yraw[(b * 2048 + n0 + it) * 256 + tid];
  __syncthreads();
  int nsub = tid & 63, cq = tid >> 6;
  for (int it = 0; it < 64; ++it) {
    int c = (it << 2) + cq;
    float v = coef2[c] * t[nsub][c] + coef2[256 + c];
    out[(b * 256 + c) * 2048 + n0 + nsub] = v > 0.f ? v : 0.f;
  }
}

extern "C" void kernel_launch(void* const* d_in, const int* in_sizes, int n_in,
                              void* d_out, int out_size, void* d_ws, size_t ws_size,
                              hipStream_t stream) {
  const float* x   = (const float*)d_in[0];
  const float* w1  = (const float*)d_in[1];
  const float* g1  = (const float*)d_in[3];
  const float* be1 = (const float*)d_in[4];
  const float* w2  = (const float*)d_in[5];
  const float* g2  = (const float*)d_in[7];
  const float* be2 = (const float*)d_in[8];
  float* out = (float*)d_out;
  char* w = (char*)d_ws;
  // workspace layout (~106.6 MB total)
  float* sqf    = (float*)(w);                 // 16384 * 4 (slot 131072 B)
  int*  idxbuf  = (int*)(w + 131072);          // 327680 * 4     = 1310720
  uint* hu      = (uint*)(w + 1441792);        // h bf16: 83886080 B
  float* xtf    = (float*)(w + 1441792);       // fp32 xT, 8 MB — ALIASES hu:
                                               // used only in knn (before conv1)
  float* yraw   = (float*)(w + 85327872);      // 4194304 * 4    = 16777216
  float* stats  = (float*)(w + 102105088);     // 4 * 256 floats
  float* coef   = (float*)(w + 102109184);     // 4 * 256 floats
  ushort* wp1   = (ushort*)(w + 102113280);    // 196608 * 2 = 393216
  ushort* wpack = (ushort*)(w + 102506496);    // 999424 * 2 = 1998848
  ushort* xbf_t = (ushort*)(w + 104505344);    // 1048576 * 2 -> end 106602496

  hipMemsetAsync(stats, 0, 4096, stream);
  prep_weights<<<4672, 256, 0, stream>>>(w1, w2, wp1, wpack);
  transpose_x<<<256, 256, 0, stream>>>(x, (uint*)xbf_t, xtf);
  sqnorm_kernel<<<64, 256, 0, stream>>>(x, sqf);
  knn_kernel<<<1024, 1024, 0, stream>>>(xtf, xbf_t, sqf, idxbuf);
  conv1_mfma<<<2048, 256, 0, stream>>>(xbf_t, idxbuf, wp1, hu);
  stats1_kernel<<<1024, 256, 0, stream>>>(hu, stats);
  finalize_kernel<<<1, 256, 0, stream>>>(stats, g1, be1, coef, 1.f / 163840.f);
  conv2_mfma<<<512, 256, 0, stream>>>(xbf_t, idxbuf, hu, coef, wpack, yraw);
  stats2_kernel<<<1024, 256, 0, stream>>>(yraw, stats + 512);
  finalize_kernel<<<1, 256, 0, stream>>>(stats + 512, g2, be2, coef + 512, 1.f / 16384.f);
  out_kernel<<<256, 256, 0, stream>>>(yraw, coef + 512, out);
}

// Round 12
// 468.986 us; speedup vs baseline: 1.1216x; 1.1216x over previous
//
#include <hip/hip_runtime.h>
#include <stdint.h>

typedef unsigned int uint;
typedef unsigned short ushort;
typedef __attribute__((ext_vector_type(8))) short short8;
typedef __attribute__((ext_vector_type(4))) float f32x4;

__device__ __forceinline__ uint f2bf(float f) {
  uint u = __float_as_uint(f);
  return (u + 0x7fffu + ((u >> 16) & 1u)) >> 16;
}
__device__ __forceinline__ float bf2f(uint us) {
  return __uint_as_float(us << 16);
}

// ---------------- weight preprocessing ----------------
// w1: (256, 128, 1, 11)  w2: (256, 128, 1, 40)
// wp1 (bf16): [t(11)][c(256)][d(64)] = w1[c][64+d][t]; then U block at
//   180224 + c*64 + d = sum_t (w1[c][d][t] - w1[c][64+d][t])
// wpack (bf16): conv2 GEMM B in per-fragment-contiguous layout:
//   gp = (((kb*2+ks)*16 + ctile)*64 + lane)*8 + j
//   c  = ctile*16 + (lane&15),  k = kb*64 + ks*32 + (lane>>4)*8 + j
//   K-order semantic (k -> source):
//     k<64:        U2[d=k][c]
//     64<=k<1344:  j-major neighbor: jn=(k-64)>>6, d=(k-64)&63 -> w2[c][64+d][jn]
//     1344<=k<3904: interleave: q=k-1344=ci*20+jj -> w2[c][ci][20+jj]
__global__ __launch_bounds__(256) void prep_weights(
    const float* __restrict__ w1, const float* __restrict__ w2,
    ushort* __restrict__ wp1, ushort* __restrict__ wpack) {
  int g = blockIdx.x * 256 + threadIdx.x;
  if (g < 180224) {
    int t = g >> 14;
    int r = g & 16383;
    int c = r >> 6, d = r & 63;
    wp1[g] = (ushort)f2bf(w1[c * 1408 + (64 + d) * 11 + t]);
  } else if (g < 196608) {
    int q = g - 180224;
    int c = q >> 6, d = q & 63;
    float s = 0.f;
    for (int t = 0; t < 11; ++t)
      s += w1[c * 1408 + d * 11 + t] - w1[c * 1408 + (64 + d) * 11 + t];
    wp1[g] = (ushort)f2bf(s);
  } else {
    int gp = g - 196608;            // < 999424 = 61*16384
    int chunk = gp >> 9;            // (kb*2+ks)*16 + ctile
    int r = gp & 511;
    int lane = r >> 3, j = r & 7;
    int kb = chunk >> 5;
    int rem = chunk & 31;
    int ks = rem >> 4, ctile = rem & 15;
    int c = ctile * 16 + (lane & 15);
    int k = kb * 64 + ks * 32 + ((lane >> 4) << 3) + j;
    float val;
    if (k < 64) {
      int d = k;
      float s = 0.f;
      for (int jn = 0; jn < 20; ++jn)
        s += w2[c * 5120 + d * 40 + jn] - w2[c * 5120 + (64 + d) * 40 + jn];
      val = s;
    } else if (k < 1344) {
      int q = k - 64; int jn = q >> 6, d = q & 63;
      val = w2[c * 5120 + (64 + d) * 40 + jn];
    } else {
      int q = k - 1344; int ci = q / 20, jj = q - ci * 20;
      val = w2[c * 5120 + ci * 40 + 20 + jj];
    }
    wpack[gp] = (ushort)f2bf(val);
  }
}

// ---------------- x transpose: bf16 [b][n][d] + fp32 [b][n][d] ----------------
__global__ __launch_bounds__(256) void transpose_x(const float* __restrict__ x,
                                                   uint* __restrict__ xtu,
                                                   float* __restrict__ xtf) {
  __shared__ float t[64][65];
  int tid = threadIdx.x;
  int blk = blockIdx.x;            // 256 = 8 b x 32 n-tiles
  int b = blk >> 5, n0 = (blk & 31) << 6;
  const float* xb = x + b * 131072;
  #pragma unroll
  for (int it = 0; it < 16; ++it) {
    int d = (it << 2) + (tid >> 6);
    int n = tid & 63;
    t[d][n] = xb[d * 2048 + n0 + n];
  }
  __syncthreads();
  #pragma unroll
  for (int it = 0; it < 8; ++it) {
    int n = (it << 3) + (tid >> 5);
    int dp = tid & 31;
    float f0 = t[2 * dp][n], f1 = t[2 * dp + 1][n];
    uint v = f2bf(f0) | (f2bf(f1) << 16);
    size_t col = (size_t)(b * 2048 + n0 + n);
    xtu[col * 32 + dp] = v;
    float2 fv; fv.x = f0; fv.y = f1;
    *(float2*)&xtf[(col << 6) + 2 * dp] = fv;
  }
}

// ---------------- squared norms (fp32, for the pre-selection only) ----------------
__global__ __launch_bounds__(256) void sqnorm_kernel(const float* __restrict__ x,
                                                     float* __restrict__ sqf) {
  int g = blockIdx.x * 256 + threadIdx.x;  // 16384
  int b = g >> 11, n = g & 2047;
  const float* xp = x + b * 131072 + n;
  float s = 0.f;
  #pragma unroll
  for (int d = 0; d < 64; ++d) { float v = xp[d * 2048]; s += v * v; }
  sqf[g] = s;
}

// ---------------- kNN v6: MFMA dists -> packed-u32 keys, min-only tournament,
// ---------------- fp64 exact re-rank of the top-31 superset ----------------
__global__ __launch_bounds__(1024) void knn_kernel(
    const float* __restrict__ xtf, const ushort* __restrict__ xbf_t,
    const float* __restrict__ sqf, int* __restrict__ idxout) {
  __shared__ uint dist[16][2048];   // 128 KB packed keys
  __shared__ int cand[16][31];
  __shared__ double dkey[16][31];
  int tid = threadIdx.x;
  int wv = tid >> 6, lane = tid & 63;
  int row0 = blockIdx.x << 4;
  int b = row0 >> 11, n0 = row0 & 2047;
  const ushort* xt = xbf_t + ((size_t)b << 17);
  const float* sqb = sqf + (b << 11);
  int m = lane & 15, quad = lane >> 4;
  short8 afr0 = *(const short8*)(xt + ((size_t)(n0 + m) << 6) + quad * 8);
  short8 afr1 = *(const short8*)(xt + ((size_t)(n0 + m) << 6) + 32 + quad * 8);
  // phase 1: wave wv computes col-tiles [wv*8, wv*8+8); writes packed keys
  for (int t = 0; t < 8; ++t) {
    int col = (((wv << 3) + t) << 4) + m;
    short8 bfr0 = *(const short8*)(xt + ((size_t)col << 6) + quad * 8);
    short8 bfr1 = *(const short8*)(xt + ((size_t)col << 6) + 32 + quad * 8);
    f32x4 c = {};
    c = __builtin_amdgcn_mfma_f32_16x16x32_bf16(afr0, bfr0, c, 0, 0, 0);
    c = __builtin_amdgcn_mfma_f32_16x16x32_bf16(afr1, bfr1, c, 0, 0, 0);
    float sq = sqb[col];
    #pragma unroll
    for (int r = 0; r < 4; ++r) {
      float f = sq - 2.f * c[r];
      uint u = __float_as_uint(f);
      uint srt = u ^ ((uint)((int)u >> 31) | 0x80000000u);
      dist[quad * 4 + r][col] = (srt & 0xFFFFF800u) | (uint)col;
    }
  }
  __syncthreads();
  uint* dr = dist[wv];
  int selfcol = n0 + wv;
  if ((selfcol & 63) == lane) dr[selfcol] = 0xFFFFFFFFu;  // kill self (own strip)
  // per-lane sorted top-4 over strip col = (l<<6)+lane
  uint v0, v1, v2, v3;
  auto scan4 = [&]() {
    v0 = v1 = v2 = v3 = 0xFFFFFFFFu;
    #pragma unroll
    for (int l = 0; l < 32; ++l) {
      uint v = dr[(l << 6) + lane];
      uint t0 = v0 > v ? v0 : v;   v0 = v0 < v ? v0 : v;
      uint t1 = v1 > t0 ? v1 : t0; v1 = v1 < t0 ? v1 : t0;
      uint t2 = v2 > t1 ? v2 : t1; v2 = v2 < t1 ? v2 : t1;
      v3 = v3 < t2 ? v3 : t2;
    }
  };
  scan4();
  for (int pick = 0; pick < 31; ++pick) {
    uint bv = v0;
    #pragma unroll
    for (int off = 32; off > 0; off >>= 1) {
      uint ov = (uint)__shfl_xor((int)bv, off);
      bv = bv < ov ? bv : ov;
    }
    int bj = (int)(bv & 2047u);
    if (lane == 0) cand[wv][pick] = bj;
    if ((bj & 63) == lane) {
      dr[bj] = 0xFFFFFFFFu;
      v0 = v1; v1 = v2; v2 = v3; v3 = 0xFFFFFFFFu;
      if (v0 == 0xFFFFFFFFu) scan4();   // ~never (4th win of one lane)
    }
  }
  __syncthreads();
  // phase 3: exact fp64 keys from fp32 xtf (contiguous 256-B columns)
  const float* xc = xtf + ((size_t)b << 17);
  const float4* xi4 = (const float4*)(xc + ((size_t)selfcol << 6));
  if (lane < 31) {
    int c = cand[wv][lane];
    const float4* xj4 = (const float4*)(xc + ((size_t)c << 6));
    double dt = 0.0, s2 = 0.0;
    #pragma unroll 4
    for (int d4 = 0; d4 < 16; ++d4) {
      float4 vj = xj4[d4];
      float4 vi = xi4[d4];
      double a0 = (double)vj.x, a1 = (double)vj.y, a2 = (double)vj.z, a3 = (double)vj.w;
      s2 += a0 * a0 + a1 * a1 + a2 * a2 + a3 * a3;
      dt += (double)vi.x * a0 + (double)vi.y * a1 + (double)vi.z * a2 + (double)vi.w * a3;
    }
    dkey[wv][lane] = s2 - 2.0 * dt;
  }
  __syncthreads();
  if (lane < 31) {
    double kl = dkey[wv][lane];
    int ci = cand[wv][lane];
    int rank = 0;
    for (int mm = 0; mm < 31; ++mm) {
      double km = dkey[wv][mm];
      int cm = cand[wv][mm];
      if (km < kl || (km == kl && cm < ci)) ++rank;
    }
    if (rank < 20) idxout[(row0 + wv) * 20 + rank] = ci;
  }
}

// ---------------- conv1 as bf16 MFMA (tap decomposition, xT staging) ----------------
__global__ __launch_bounds__(256) void conv1_mfma(
    const ushort* __restrict__ xbf_t, const int* __restrict__ idxbuf,
    const ushort* __restrict__ wp1, uint* __restrict__ hu) {
  __shared__ ushort sl[21][16][72];   // 48384 B; rows 144 B (16-B aligned)
  __shared__ int nidx[16][20];
  int tid = threadIdx.x;
  int pg = blockIdx.x >> 1;
  int cg = blockIdx.x & 1;
  int p0 = pg << 4;
  int b = p0 >> 11, n0 = p0 & 2047;
  const ushort* xt = xbf_t + ((size_t)b << 17);
  for (int v = tid; v < 320; v += 256) {
    int p = v / 20, j = v - p * 20;
    nidx[p][j] = idxbuf[(p0 + p) * 20 + j];
  }
  __syncthreads();
  // 21 slices x 16 points x 8 chunks of short8
  for (int v = tid; v < 2688; v += 256) {
    int s = v >> 7;
    int r = v & 127;
    int p = r >> 3, i = r & 7;
    int col = (s == 0) ? (n0 + p) : nidx[p][s - 1];
    *(short8*)&sl[s][p][i << 3] =
        *(const short8*)(xt + ((size_t)col << 6) + (i << 3));
  }
  __syncthreads();
  int lane = tid & 63, wave = tid >> 6;
  int m = lane & 15, quad = lane >> 4;
  int ch0 = (cg << 7) + (wave << 4) + m;    // + ct*64
  f32x4 acc[10][2] = {};
  f32x4 cacc[2] = {};
  {
    short8 a0 = *(const short8*)&sl[0][m][quad * 8];
    short8 a1 = *(const short8*)&sl[0][m][32 + quad * 8];
    #pragma unroll
    for (int ct = 0; ct < 2; ++ct) {
      const ushort* urow = wp1 + 180224 + (ch0 + ct * 64) * 64 + quad * 8;
      short8 b0 = *(const short8*)(urow);
      short8 b1 = *(const short8*)(urow + 32);
      cacc[ct] = __builtin_amdgcn_mfma_f32_16x16x32_bf16(a0, b0, cacc[ct], 0, 0, 0);
      cacc[ct] = __builtin_amdgcn_mfma_f32_16x16x32_bf16(a1, b1, cacc[ct], 0, 0, 0);
    }
  }
  #pragma unroll
  for (int t = 0; t < 11; ++t) {
    short8 b0[2], b1[2];
    #pragma unroll
    for (int ct = 0; ct < 2; ++ct) {
      const ushort* brow = wp1 + t * 16384 + (ch0 + ct * 64) * 64 + quad * 8;
      b0[ct] = *(const short8*)(brow);
      b1[ct] = *(const short8*)(brow + 32);
    }
    #pragma unroll
    for (int ko = 0; ko < 10; ++ko) {
      int s = 1 + ko + t;
      short8 a0 = *(const short8*)&sl[s][m][quad * 8];
      short8 a1 = *(const short8*)&sl[s][m][32 + quad * 8];
      #pragma unroll
      for (int ct = 0; ct < 2; ++ct) {
        acc[ko][ct] = __builtin_amdgcn_mfma_f32_16x16x32_bf16(a0, b0[ct], acc[ko][ct], 0, 0, 0);
        acc[ko][ct] = __builtin_amdgcn_mfma_f32_16x16x32_bf16(a1, b1[ct], acc[ko][ct], 0, 0, 0);
      }
    }
  }
  // epilogue: D layout col=lane&15 -> channel, row=quad*4+r -> point
  #pragma unroll
  for (int ct = 0; ct < 2; ++ct) {
    int c = ch0 + ct * 64;
    #pragma unroll
    for (int r = 0; r < 4; ++r) {
      int p = (quad << 2) + r;
      int base5 = ((p0 + p) * 256 + c) * 5;
      float cc = cacc[ct][r];
      #pragma unroll
      for (int q = 0; q < 5; ++q) {
        float f0 = acc[2 * q][ct][r] + cc;
        float f1 = acc[2 * q + 1][ct][r] + cc;
        hu[base5 + q] = f2bf(f0) | (f2bf(f1) << 16);
      }
    }
  }
}

// ---------------- BN stats ----------------
__global__ __launch_bounds__(256) void stats1_kernel(const uint* __restrict__ hu,
                                                     float* __restrict__ stats) {
  int c = threadIdx.x;
  float s = 0.f, ss = 0.f;
  for (int row = blockIdx.x; row < 16384; row += 1024) {
    int base = (row * 256 + c) * 5;
    #pragma unroll
    for (int q = 0; q < 5; ++q) {
      uint v = hu[base + q];
      float f0 = bf2f(v & 0xffffu), f1 = bf2f(v >> 16);
      s += f0 + f1; ss += f0 * f0 + f1 * f1;
    }
  }
  atomicAdd(&stats[c], s);
  atomicAdd(&stats[256 + c], ss);
}

__global__ void finalize_kernel(const float* __restrict__ stats,
                                const float* __restrict__ gamma,
                                const float* __restrict__ beta,
                                float* __restrict__ coef, float inv_count) {
  int c = threadIdx.x;
  float m = stats[c] * inv_count;
  float var = stats[256 + c] * inv_count - m * m;
  float a = gamma[c] * rsqrtf(var + 1e-5f);
  coef[c] = a;
  coef[256 + c] = beta[c] - m * a;
}

// ---------------- conv2 as bf16 MFMA GEMM v3 ----------------
// Block: 64 points x 256 ch, 512 threads (8 waves x 32 ch), 256 blocks = 1/CU.
// B-frags contiguous 1-KB chunks (fully-coalesced, 100% line utilization),
// reused across 4 m-tiles. A staged in 4-kb double-buffered phases.
__global__ __launch_bounds__(512) void conv2_mfma(
    const ushort* __restrict__ xbf_t, const int* __restrict__ idxbuf,
    const uint* __restrict__ hu, const float* __restrict__ coef1,
    const ushort* __restrict__ wpack, float* __restrict__ yraw) {
  __shared__ ushort As[2][4][64][72];   // 73728 B
  __shared__ int nidx[64][20];
  __shared__ float cf[512];
  int tid = threadIdx.x;
  int p0 = blockIdx.x << 6;          // 64 points per block
  int b = p0 >> 11, n0 = p0 & 2047;
  const ushort* xt = xbf_t + ((size_t)b << 17);

  cf[tid] = coef1[tid];
  for (int v = tid; v < 1280; v += 512) {
    int p = v / 20, j = v - p * 20;
    nidx[p][j] = idxbuf[(p0 + p) * 20 + j];
  }
  __syncthreads();

  int pp = tid >> 3;                 // point 0..63
  int off = (tid & 7) << 3;          // 8-col chunk within 64

  // stage kbs [phase*4, phase*4+4) ∩ [0,61): loads hoisted, then transforms
  auto build = [&](int phase, int buf) {
    int kb0 = phase << 2;
    short8 xv[4];
    uint4 hv[4];
    #pragma unroll
    for (int kc = 0; kc < 4; ++kc) {
      int kb = kb0 + kc;
      if (kb >= 61) continue;
      if (kb < 21) {
        int col = (kb == 0) ? (n0 + pp) : nidx[pp][kb - 1];
        xv[kc] = *(const short8*)(xt + ((size_t)col << 6) + off);
      } else {
        int q0 = (kb - 21) * 64 + off;
        hv[kc] = *(const uint4*)(hu + (size_t)(p0 + pp) * 1280 + (q0 >> 1));
      }
    }
    #pragma unroll
    for (int kc = 0; kc < 4; ++kc) {
      int kb = kb0 + kc;
      if (kb >= 61) continue;
      if (kb < 21) {
        *(short8*)&As[buf][kc][pp][off] = xv[kc];
      } else {
        int q0 = (kb - 21) * 64 + off;
        uint4 hvv = hv[kc];
        float f[8];
        f[0] = bf2f(hvv.x & 0xffffu); f[1] = bf2f(hvv.x >> 16);
        f[2] = bf2f(hvv.y & 0xffffu); f[3] = bf2f(hvv.y >> 16);
        f[4] = bf2f(hvv.z & 0xffffu); f[5] = bf2f(hvv.z >> 16);
        f[6] = bf2f(hvv.w & 0xffffu); f[7] = bf2f(hvv.w >> 16);
        ushort o[8];
        #pragma unroll
        for (int i = 0; i < 8; ++i) {
          int ch = (q0 + i) / 10;
          float vv = f[i] * cf[ch] + cf[256 + ch];
          vv = vv > 0.f ? vv : 0.01f * vv;
          o[i] = (ushort)f2bf(vv);
        }
        *(short8*)&As[buf][kc][pp][off] = *(short8*)o;
      }
    }
  };

  int lane = tid & 63, wave = tid >> 6;
  int m = lane & 15, quad = lane >> 4;
  f32x4 acc[4][2] = {};

  build(0, 0);
  __syncthreads();
  for (int phase = 0; phase < 16; ++phase) {
    int buf = phase & 1;
    if (phase < 15) build(phase + 1, buf ^ 1);
    #pragma unroll
    for (int kc = 0; kc < 4; ++kc) {
      int kb = (phase << 2) + kc;
      if (kb >= 61) break;
      #pragma unroll
      for (int ks = 0; ks < 2; ++ks) {
        short8 afr[4];
        #pragma unroll
        for (int mt = 0; mt < 4; ++mt)
          afr[mt] = *(const short8*)&As[buf][kc][mt * 16 + m][ks * 32 + quad * 8];
        #pragma unroll
        for (int nt = 0; nt < 2; ++nt) {
          // contiguous 1-KB fragment: chunk = (kb*2+ks)*16 + wave*2+nt
          const ushort* bp = wpack +
              (((size_t)((kb * 2 + ks) * 16 + (wave << 1) + nt)) << 9) + lane * 8;
          short8 bfr = *(const short8*)bp;
          #pragma unroll
          for (int mt = 0; mt < 4; ++mt)
            acc[mt][nt] = __builtin_amdgcn_mfma_f32_16x16x32_bf16(afr[mt], bfr, acc[mt][nt], 0, 0, 0);
        }
      }
    }
    __syncthreads();
  }
  // epilogue: D col=lane&15 -> channel, row=quad*4+r -> point
  #pragma unroll
  for (int mt = 0; mt < 4; ++mt) {
    #pragma unroll
    for (int nt = 0; nt < 2; ++nt) {
      int col = (wave << 5) + nt * 16 + m;
      #pragma unroll
      for (int r = 0; r < 4; ++r) {
        int prow = mt * 16 + quad * 4 + r;
        yraw[(size_t)(p0 + prow) * 256 + col] = acc[mt][nt][r];
      }
    }
  }
}

__global__ __launch_bounds__(256) void stats2_kernel(const float* __restrict__ yraw,
                                                     float* __restrict__ stats) {
  int c = threadIdx.x;
  float s = 0.f, ss = 0.f;
  for (int row = blockIdx.x; row < 16384; row += 1024) {
    float v = yraw[row * 256 + c];
    s += v; ss += v * v;
  }
  atomicAdd(&stats[c], s);
  atomicAdd(&stats[256 + c], ss);
}

// ---------------- BN2 + relu + transpose to (b, c, n) ----------------
__global__ __launch_bounds__(256) void out_kernel(const float* __restrict__ yraw,
                                                  const float* __restrict__ coef2,
                                                  float* __restrict__ out) {
  __shared__ float t[64][257];
  int tid = threadIdx.x;
  int blk = blockIdx.x;            // 256 = 8 b x 32 n-tiles
  int b = blk >> 5, n0 = (blk & 31) << 6;
  for (int it = 0; it < 64; ++it)
    t[it][tid] = yraw[(b * 2048 + n0 + it) * 256 + tid];
  __syncthreads();
  int nsub = tid & 63, cq = tid >> 6;
  for (int it = 0; it < 64; ++it) {
    int c = (it << 2) + cq;
    float v = coef2[c] * t[nsub][c] + coef2[256 + c];
    out[(b * 256 + c) * 2048 + n0 + nsub] = v > 0.f ? v : 0.f;
  }
}

extern "C" void kernel_launch(void* const* d_in, const int* in_sizes, int n_in,
                              void* d_out, int out_size, void* d_ws, size_t ws_size,
                              hipStream_t stream) {
  const float* x   = (const float*)d_in[0];
  const float* w1  = (const float*)d_in[1];
  const float* g1  = (const float*)d_in[3];
  const float* be1 = (const float*)d_in[4];
  const float* w2  = (const float*)d_in[5];
  const float* g2  = (const float*)d_in[7];
  const float* be2 = (const float*)d_in[8];
  float* out = (float*)d_out;
  char* w = (char*)d_ws;
  // workspace layout (~106.6 MB total)
  float* sqf    = (float*)(w);                 // 16384 * 4 (slot 131072 B)
  int*  idxbuf  = (int*)(w + 131072);          // 327680 * 4     = 1310720
  uint* hu      = (uint*)(w + 1441792);        // h bf16: 83886080 B
  float* xtf    = (float*)(w + 1441792);       // fp32 xT, 8 MB — ALIASES hu:
                                               // used only in knn (before conv1)
  float* yraw   = (float*)(w + 85327872);      // 4194304 * 4    = 16777216
  float* stats  = (float*)(w + 102105088);     // 4 * 256 floats
  float* coef   = (float*)(w + 102109184);     // 4 * 256 floats
  ushort* wp1   = (ushort*)(w + 102113280);    // 196608 * 2 = 393216
  ushort* wpack = (ushort*)(w + 102506496);    // 999424 * 2 = 1998848
  ushort* xbf_t = (ushort*)(w + 104505344);    // 1048576 * 2 -> end 106602496

  hipMemsetAsync(stats, 0, 4096, stream);
  prep_weights<<<4672, 256, 0, stream>>>(w1, w2, wp1, wpack);
  transpose_x<<<256, 256, 0, stream>>>(x, (uint*)xbf_t, xtf);
  sqnorm_kernel<<<64, 256, 0, stream>>>(x, sqf);
  knn_kernel<<<1024, 1024, 0, stream>>>(xtf, xbf_t, sqf, idxbuf);
  conv1_mfma<<<2048, 256, 0, stream>>>(xbf_t, idxbuf, wp1, hu);
  stats1_kernel<<<1024, 256, 0, stream>>>(hu, stats);
  finalize_kernel<<<1, 256, 0, stream>>>(stats, g1, be1, coef, 1.f / 163840.f);
  conv2_mfma<<<256, 512, 0, stream>>>(xbf_t, idxbuf, hu, coef, wpack, yraw);
  stats2_kernel<<<1024, 256, 0, stream>>>(yraw, stats + 512);
  finalize_kernel<<<1, 256, 0, stream>>>(stats + 512, g2, be2, coef + 512, 1.f / 16384.f);
  out_kernel<<<256, 256, 0, stream>>>(yraw, coef + 512, out);
}

// Round 13
// 451.252 us; speedup vs baseline: 1.1657x; 1.0393x over previous
//
#include <hip/hip_runtime.h>
#include <stdint.h>

typedef unsigned int uint;
typedef unsigned short ushort;
typedef __attribute__((ext_vector_type(8))) short short8;
typedef __attribute__((ext_vector_type(4))) float f32x4;

__device__ __forceinline__ uint f2bf(float f) {
  uint u = __float_as_uint(f);
  return (u + 0x7fffu + ((u >> 16) & 1u)) >> 16;
}
__device__ __forceinline__ float bf2f(uint us) {
  return __uint_as_float(us << 16);
}

// ---------------- weight preprocessing ----------------
// w1: (256, 128, 1, 11)  w2: (256, 128, 1, 40)
// wp1 (bf16): [t(11)][c(256)][d(64)] = w1[c][64+d][t]; then U block at
//   180224 + c*64 + d = sum_t (w1[c][d][t] - w1[c][64+d][t])
// wpack (bf16): conv2 GEMM B in per-fragment-contiguous layout:
//   gp = (((kb*2+ks)*16 + ctile)*64 + lane)*8 + j
//   c  = ctile*16 + (lane&15),  k = kb*64 + ks*32 + (lane>>4)*8 + j
//   K-order semantic (k -> source):
//     k<64:        U2[d=k][c]
//     64<=k<1344:  j-major neighbor: jn=(k-64)>>6, d=(k-64)&63 -> w2[c][64+d][jn]
//     1344<=k<3904: interleave: q=k-1344=ci*20+jj -> w2[c][ci][20+jj]
__global__ __launch_bounds__(256) void prep_weights(
    const float* __restrict__ w1, const float* __restrict__ w2,
    ushort* __restrict__ wp1, ushort* __restrict__ wpack) {
  int g = blockIdx.x * 256 + threadIdx.x;
  if (g < 180224) {
    int t = g >> 14;
    int r = g & 16383;
    int c = r >> 6, d = r & 63;
    wp1[g] = (ushort)f2bf(w1[c * 1408 + (64 + d) * 11 + t]);
  } else if (g < 196608) {
    int q = g - 180224;
    int c = q >> 6, d = q & 63;
    float s = 0.f;
    for (int t = 0; t < 11; ++t)
      s += w1[c * 1408 + d * 11 + t] - w1[c * 1408 + (64 + d) * 11 + t];
    wp1[g] = (ushort)f2bf(s);
  } else {
    int gp = g - 196608;            // < 999424 = 61*16384
    int chunk = gp >> 9;            // (kb*2+ks)*16 + ctile
    int r = gp & 511;
    int lane = r >> 3, j = r & 7;
    int kb = chunk >> 5;
    int rem = chunk & 31;
    int ks = rem >> 4, ctile = rem & 15;
    int c = ctile * 16 + (lane & 15);
    int k = kb * 64 + ks * 32 + ((lane >> 4) << 3) + j;
    float val;
    if (k < 64) {
      int d = k;
      float s = 0.f;
      for (int jn = 0; jn < 20; ++jn)
        s += w2[c * 5120 + d * 40 + jn] - w2[c * 5120 + (64 + d) * 40 + jn];
      val = s;
    } else if (k < 1344) {
      int q = k - 64; int jn = q >> 6, d = q & 63;
      val = w2[c * 5120 + (64 + d) * 40 + jn];
    } else {
      int q = k - 1344; int ci = q / 20, jj = q - ci * 20;
      val = w2[c * 5120 + ci * 40 + 20 + jj];
    }
    wpack[gp] = (ushort)f2bf(val);
  }
}

// ---------------- x transpose: bf16 [b][n][d] + fp32 [b][n][d] + sqnorm ----------------
__global__ __launch_bounds__(256) void transpose_x(const float* __restrict__ x,
                                                   uint* __restrict__ xtu,
                                                   float* __restrict__ xtf,
                                                   float* __restrict__ sqf) {
  __shared__ float t[64][65];
  int tid = threadIdx.x;
  int blk = blockIdx.x;            // 256 = 8 b x 32 n-tiles
  int b = blk >> 5, n0 = (blk & 31) << 6;
  const float* xb = x + b * 131072;
  #pragma unroll
  for (int it = 0; it < 16; ++it) {
    int d = (it << 2) + (tid >> 6);
    int n = tid & 63;
    t[d][n] = xb[d * 2048 + n0 + n];
  }
  __syncthreads();
  #pragma unroll
  for (int it = 0; it < 8; ++it) {
    int n = (it << 3) + (tid >> 5);
    int dp = tid & 31;
    float f0 = t[2 * dp][n], f1 = t[2 * dp + 1][n];
    uint v = f2bf(f0) | (f2bf(f1) << 16);
    size_t col = (size_t)(b * 2048 + n0 + n);
    xtu[col * 32 + dp] = v;
    float2 fv; fv.x = f0; fv.y = f1;
    *(float2*)&xtf[(col << 6) + 2 * dp] = fv;
    float s = f0 * f0 + f1 * f1;
    #pragma unroll
    for (int off = 16; off > 0; off >>= 1) s += __shfl_xor(s, off);
    if (dp == 0) sqf[col] = s;
  }
}

// ---------------- kNN v7: MFMA dists -> packed-u32 keys, 2-winner butterfly,
// ---------------- fp64 exact re-rank of the top-32 superset ----------------
// key = (sortable_fp32 & ~0x7FF) | col. Self killed up front. 16 rounds x 2
// winners = 32 candidates. Per-lane sorted top-6 in registers; invariant:
// (v0,v1) are the two smallest unkilled keys of the lane's strip (rescan when
// v1 hits sentinel). fp64 re-rank restores exact reference order.
__global__ __launch_bounds__(1024) void knn_kernel(
    const float* __restrict__ xtf, const ushort* __restrict__ xbf_t,
    const float* __restrict__ sqf, int* __restrict__ idxout) {
  __shared__ uint dist[16][2048];   // 128 KB packed keys
  __shared__ int cand[16][32];
  __shared__ double dkey[16][32];
  int tid = threadIdx.x;
  int wv = tid >> 6, lane = tid & 63;
  int row0 = blockIdx.x << 4;
  int b = row0 >> 11, n0 = row0 & 2047;
  const ushort* xt = xbf_t + ((size_t)b << 17);
  const float* sqb = sqf + (b << 11);
  int m = lane & 15, quad = lane >> 4;
  short8 afr0 = *(const short8*)(xt + ((size_t)(n0 + m) << 6) + quad * 8);
  short8 afr1 = *(const short8*)(xt + ((size_t)(n0 + m) << 6) + 32 + quad * 8);
  // phase 1: wave wv computes col-tiles [wv*8, wv*8+8); writes packed keys
  for (int t = 0; t < 8; ++t) {
    int col = (((wv << 3) + t) << 4) + m;
    short8 bfr0 = *(const short8*)(xt + ((size_t)col << 6) + quad * 8);
    short8 bfr1 = *(const short8*)(xt + ((size_t)col << 6) + 32 + quad * 8);
    f32x4 c = {};
    c = __builtin_amdgcn_mfma_f32_16x16x32_bf16(afr0, bfr0, c, 0, 0, 0);
    c = __builtin_amdgcn_mfma_f32_16x16x32_bf16(afr1, bfr1, c, 0, 0, 0);
    float sq = sqb[col];
    #pragma unroll
    for (int r = 0; r < 4; ++r) {
      float f = sq - 2.f * c[r];
      uint u = __float_as_uint(f);
      uint srt = u ^ ((uint)((int)u >> 31) | 0x80000000u);
      dist[quad * 4 + r][col] = (srt & 0xFFFFF800u) | (uint)col;
    }
  }
  __syncthreads();
  uint* dr = dist[wv];
  int selfcol = n0 + wv;
  if ((selfcol & 63) == lane) dr[selfcol] = 0xFFFFFFFFu;  // kill self (own strip)
  // per-lane sorted top-6 over strip col = (l<<6)+lane
  uint v0, v1, v2, v3, v4, v5;
  auto scan6 = [&]() {
    v0 = v1 = v2 = v3 = v4 = v5 = 0xFFFFFFFFu;
    #pragma unroll
    for (int l = 0; l < 32; ++l) {
      uint v = dr[(l << 6) + lane];
      uint t0 = v0 > v ? v0 : v;   v0 = v0 < v ? v0 : v;
      uint t1 = v1 > t0 ? v1 : t0; v1 = v1 < t0 ? v1 : t0;
      uint t2 = v2 > t1 ? v2 : t1; v2 = v2 < t1 ? v2 : t1;
      uint t3 = v3 > t2 ? v3 : t2; v3 = v3 < t2 ? v3 : t2;
      uint t4 = v4 > t3 ? v4 : t3; v4 = v4 < t3 ? v4 : t3;
      v5 = v5 < t4 ? v5 : t4;
    }
  };
  scan6();
  for (int round = 0; round < 16; ++round) {
    uint w0 = v0, w1 = v1;
    #pragma unroll
    for (int off = 32; off > 0; off >>= 1) {
      uint o0 = (uint)__shfl_xor((int)w0, off);
      uint o1 = (uint)__shfl_xor((int)w1, off);
      uint lo = w0 < o0 ? w0 : o0;
      uint hi = w0 < o0 ? o0 : w0;
      uint mn1 = w1 < o1 ? w1 : o1;
      w0 = lo;
      w1 = hi < mn1 ? hi : mn1;
    }
    if (lane == 0) {
      cand[wv][2 * round] = (int)(w0 & 2047u);
      cand[wv][2 * round + 1] = (int)(w1 & 2047u);
    }
    int own0 = ((w0 & 63u) == (uint)lane) ? 1 : 0;
    int own1 = ((w1 & 63u) == (uint)lane) ? 1 : 0;
    if (own0) dr[w0 & 2047u] = 0xFFFFFFFFu;
    if (own1) dr[w1 & 2047u] = 0xFFFFFFFFu;
    int cnt = own0 + own1;
    if (cnt == 1) { v0 = v1; v1 = v2; v2 = v3; v3 = v4; v4 = v5; v5 = 0xFFFFFFFFu; }
    else if (cnt == 2) { v0 = v2; v1 = v3; v2 = v4; v3 = v5; v4 = 0xFFFFFFFFu; v5 = 0xFFFFFFFFu; }
    if (v1 == 0xFFFFFFFFu) scan6();   // need two valid spares (rare)
  }
  __syncthreads();
  // phase 3: exact fp64 keys from fp32 xtf (contiguous 256-B columns)
  const float* xc = xtf + ((size_t)b << 17);
  const float4* xi4 = (const float4*)(xc + ((size_t)selfcol << 6));
  if (lane < 32) {
    int c = cand[wv][lane];
    const float4* xj4 = (const float4*)(xc + ((size_t)c << 6));
    double dt = 0.0, s2 = 0.0;
    #pragma unroll 4
    for (int d4 = 0; d4 < 16; ++d4) {
      float4 vj = xj4[d4];
      float4 vi = xi4[d4];
      double a0 = (double)vj.x, a1 = (double)vj.y, a2 = (double)vj.z, a3 = (double)vj.w;
      s2 += a0 * a0 + a1 * a1 + a2 * a2 + a3 * a3;
      dt += (double)vi.x * a0 + (double)vi.y * a1 + (double)vi.z * a2 + (double)vi.w * a3;
    }
    dkey[wv][lane] = s2 - 2.0 * dt;
  }
  __syncthreads();
  if (lane < 32) {
    double kl = dkey[wv][lane];
    int ci = cand[wv][lane];
    int rank = 0;
    for (int mm = 0; mm < 32; ++mm) {
      double km = dkey[wv][mm];
      int cm = cand[wv][mm];
      if (km < kl || (km == kl && cm < ci)) ++rank;
    }
    if (rank < 20) idxout[(row0 + wv) * 20 + rank] = ci;
  }
}

// ---------------- conv1 as bf16 MFMA (tap decomposition, single staging) ----------------
// Block: 16 points x 256 channels; slices staged ONCE, channel halves looped.
__global__ __launch_bounds__(256) void conv1_mfma(
    const ushort* __restrict__ xbf_t, const int* __restrict__ idxbuf,
    const ushort* __restrict__ wp1, uint* __restrict__ hu) {
  __shared__ ushort sl[21][16][72];   // 48384 B; rows 144 B (16-B aligned)
  __shared__ int nidx[16][20];
  int tid = threadIdx.x;
  int p0 = blockIdx.x << 4;
  int b = p0 >> 11, n0 = p0 & 2047;
  const ushort* xt = xbf_t + ((size_t)b << 17);
  for (int v = tid; v < 320; v += 256) {
    int p = v / 20, j = v - p * 20;
    nidx[p][j] = idxbuf[(p0 + p) * 20 + j];
  }
  __syncthreads();
  // 21 slices x 16 points x 8 chunks of short8
  for (int v = tid; v < 2688; v += 256) {
    int s = v >> 7;
    int r = v & 127;
    int p = r >> 3, i = r & 7;
    int col = (s == 0) ? (n0 + p) : nidx[p][s - 1];
    *(short8*)&sl[s][p][i << 3] =
        *(const short8*)(xt + ((size_t)col << 6) + (i << 3));
  }
  __syncthreads();
  int lane = tid & 63, wave = tid >> 6;
  int m = lane & 15, quad = lane >> 4;
  #pragma unroll 1
  for (int cg2 = 0; cg2 < 2; ++cg2) {
    int ch0 = (cg2 << 7) + (wave << 4) + m;    // + ct*64
    f32x4 acc[10][2] = {};
    f32x4 cacc[2] = {};
    {
      short8 a0 = *(const short8*)&sl[0][m][quad * 8];
      short8 a1 = *(const short8*)&sl[0][m][32 + quad * 8];
      #pragma unroll
      for (int ct = 0; ct < 2; ++ct) {
        const ushort* urow = wp1 + 180224 + (ch0 + ct * 64) * 64 + quad * 8;
        short8 b0 = *(const short8*)(urow);
        short8 b1 = *(const short8*)(urow + 32);
        cacc[ct] = __builtin_amdgcn_mfma_f32_16x16x32_bf16(a0, b0, cacc[ct], 0, 0, 0);
        cacc[ct] = __builtin_amdgcn_mfma_f32_16x16x32_bf16(a1, b1, cacc[ct], 0, 0, 0);
      }
    }
    #pragma unroll
    for (int t = 0; t < 11; ++t) {
      short8 b0[2], b1[2];
      #pragma unroll
      for (int ct = 0; ct < 2; ++ct) {
        const ushort* brow = wp1 + t * 16384 + (ch0 + ct * 64) * 64 + quad * 8;
        b0[ct] = *(const short8*)(brow);
        b1[ct] = *(const short8*)(brow + 32);
      }
      #pragma unroll
      for (int ko = 0; ko < 10; ++ko) {
        int s = 1 + ko + t;
        short8 a0 = *(const short8*)&sl[s][m][quad * 8];
        short8 a1 = *(const short8*)&sl[s][m][32 + quad * 8];
        #pragma unroll
        for (int ct = 0; ct < 2; ++ct) {
          acc[ko][ct] = __builtin_amdgcn_mfma_f32_16x16x32_bf16(a0, b0[ct], acc[ko][ct], 0, 0, 0);
          acc[ko][ct] = __builtin_amdgcn_mfma_f32_16x16x32_bf16(a1, b1[ct], acc[ko][ct], 0, 0, 0);
        }
      }
    }
    // epilogue: D layout col=lane&15 -> channel, row=quad*4+r -> point
    #pragma unroll
    for (int ct = 0; ct < 2; ++ct) {
      int c = ch0 + ct * 64;
      #pragma unroll
      for (int r = 0; r < 4; ++r) {
        int p = (quad << 2) + r;
        int base5 = ((p0 + p) * 256 + c) * 5;
        float cc = cacc[ct][r];
        #pragma unroll
        for (int q = 0; q < 5; ++q) {
          float f0 = acc[2 * q][ct][r] + cc;
          float f1 = acc[2 * q + 1][ct][r] + cc;
          hu[base5 + q] = f2bf(f0) | (f2bf(f1) << 16);
        }
      }
    }
  }
}

// ---------------- BN stats ----------------
__global__ __launch_bounds__(256) void stats1_kernel(const uint* __restrict__ hu,
                                                     float* __restrict__ stats) {
  int c = threadIdx.x;
  float s = 0.f, ss = 0.f;
  for (int row = blockIdx.x; row < 16384; row += 1024) {
    int base = (row * 256 + c) * 5;
    #pragma unroll
    for (int q = 0; q < 5; ++q) {
      uint v = hu[base + q];
      float f0 = bf2f(v & 0xffffu), f1 = bf2f(v >> 16);
      s += f0 + f1; ss += f0 * f0 + f1 * f1;
    }
  }
  atomicAdd(&stats[c], s);
  atomicAdd(&stats[256 + c], ss);
}

__global__ void finalize_kernel(const float* __restrict__ stats,
                                const float* __restrict__ gamma,
                                const float* __restrict__ beta,
                                float* __restrict__ coef, float inv_count) {
  int c = threadIdx.x;
  float m = stats[c] * inv_count;
  float var = stats[256 + c] * inv_count - m * m;
  float a = gamma[c] * rsqrtf(var + 1e-5f);
  coef[c] = a;
  coef[256 + c] = beta[c] - m * a;
}

// ---------------- conv2 as bf16 MFMA GEMM v3 ----------------
// Block: 64 points x 256 ch, 512 threads (8 waves x 32 ch), 256 blocks = 1/CU.
// B-frags contiguous 1-KB chunks (fully-coalesced), reused across 4 m-tiles.
__global__ __launch_bounds__(512) void conv2_mfma(
    const ushort* __restrict__ xbf_t, const int* __restrict__ idxbuf,
    const uint* __restrict__ hu, const float* __restrict__ coef1,
    const ushort* __restrict__ wpack, float* __restrict__ yraw) {
  __shared__ ushort As[2][4][64][72];   // 73728 B
  __shared__ int nidx[64][20];
  __shared__ float cf[512];
  int tid = threadIdx.x;
  int p0 = blockIdx.x << 6;          // 64 points per block
  int b = p0 >> 11, n0 = p0 & 2047;
  const ushort* xt = xbf_t + ((size_t)b << 17);

  cf[tid] = coef1[tid];
  for (int v = tid; v < 1280; v += 512) {
    int p = v / 20, j = v - p * 20;
    nidx[p][j] = idxbuf[(p0 + p) * 20 + j];
  }
  __syncthreads();

  int pp = tid >> 3;                 // point 0..63
  int off = (tid & 7) << 3;          // 8-col chunk within 64

  // stage kbs [phase*4, phase*4+4) ∩ [0,61): loads hoisted, then transforms
  auto build = [&](int phase, int buf) {
    int kb0 = phase << 2;
    short8 xv[4];
    uint4 hv[4];
    #pragma unroll
    for (int kc = 0; kc < 4; ++kc) {
      int kb = kb0 + kc;
      if (kb >= 61) continue;
      if (kb < 21) {
        int col = (kb == 0) ? (n0 + pp) : nidx[pp][kb - 1];
        xv[kc] = *(const short8*)(xt + ((size_t)col << 6) + off);
      } else {
        int q0 = (kb - 21) * 64 + off;
        hv[kc] = *(const uint4*)(hu + (size_t)(p0 + pp) * 1280 + (q0 >> 1));
      }
    }
    #pragma unroll
    for (int kc = 0; kc < 4; ++kc) {
      int kb = kb0 + kc;
      if (kb >= 61) continue;
      if (kb < 21) {
        *(short8*)&As[buf][kc][pp][off] = xv[kc];
      } else {
        int q0 = (kb - 21) * 64 + off;
        uint4 hvv = hv[kc];
        float f[8];
        f[0] = bf2f(hvv.x & 0xffffu); f[1] = bf2f(hvv.x >> 16);
        f[2] = bf2f(hvv.y & 0xffffu); f[3] = bf2f(hvv.y >> 16);
        f[4] = bf2f(hvv.z & 0xffffu); f[5] = bf2f(hvv.z >> 16);
        f[6] = bf2f(hvv.w & 0xffffu); f[7] = bf2f(hvv.w >> 16);
        ushort o[8];
        #pragma unroll
        for (int i = 0; i < 8; ++i) {
          int ch = (q0 + i) / 10;
          float vv = f[i] * cf[ch] + cf[256 + ch];
          vv = vv > 0.f ? vv : 0.01f * vv;
          o[i] = (ushort)f2bf(vv);
        }
        *(short8*)&As[buf][kc][pp][off] = *(short8*)o;
      }
    }
  };

  int lane = tid & 63, wave = tid >> 6;
  int m = lane & 15, quad = lane >> 4;
  f32x4 acc[4][2] = {};

  build(0, 0);
  __syncthreads();
  for (int phase = 0; phase < 16; ++phase) {
    int buf = phase & 1;
    if (phase < 15) build(phase + 1, buf ^ 1);
    #pragma unroll
    for (int kc = 0; kc < 4; ++kc) {
      int kb = (phase << 2) + kc;
      if (kb >= 61) break;
      #pragma unroll
      for (int ks = 0; ks < 2; ++ks) {
        short8 afr[4];
        #pragma unroll
        for (int mt = 0; mt < 4; ++mt)
          afr[mt] = *(const short8*)&As[buf][kc][mt * 16 + m][ks * 32 + quad * 8];
        #pragma unroll
        for (int nt = 0; nt < 2; ++nt) {
          const ushort* bp = wpack +
              (((size_t)((kb * 2 + ks) * 16 + (wave << 1) + nt)) << 9) + lane * 8;
          short8 bfr = *(const short8*)bp;
          #pragma unroll
          for (int mt = 0; mt < 4; ++mt)
            acc[mt][nt] = __builtin_amdgcn_mfma_f32_16x16x32_bf16(afr[mt], bfr, acc[mt][nt], 0, 0, 0);
        }
      }
    }
    __syncthreads();
  }
  // epilogue: D col=lane&15 -> channel, row=quad*4+r -> point
  #pragma unroll
  for (int mt = 0; mt < 4; ++mt) {
    #pragma unroll
    for (int nt = 0; nt < 2; ++nt) {
      int col = (wave << 5) + nt * 16 + m;
      #pragma unroll
      for (int r = 0; r < 4; ++r) {
        int prow = mt * 16 + quad * 4 + r;
        yraw[(size_t)(p0 + prow) * 256 + col] = acc[mt][nt][r];
      }
    }
  }
}

__global__ __launch_bounds__(256) void stats2_kernel(const float* __restrict__ yraw,
                                                     float* __restrict__ stats) {
  int c = threadIdx.x;
  float s = 0.f, ss = 0.f;
  for (int row = blockIdx.x; row < 16384; row += 1024) {
    float v = yraw[row * 256 + c];
    s += v; ss += v * v;
  }
  atomicAdd(&stats[c], s);
  atomicAdd(&stats[256 + c], ss);
}

// ---------------- BN2 + relu + transpose to (b, c, n) ----------------
__global__ __launch_bounds__(256) void out_kernel(const float* __restrict__ yraw,
                                                  const float* __restrict__ coef2,
                                                  float* __restrict__ out) {
  __shared__ float t[64][257];
  int tid = threadIdx.x;
  int blk = blockIdx.x;            // 256 = 8 b x 32 n-tiles
  int b = blk >> 5, n0 = (blk & 31) << 6;
  for (int it = 0; it < 64; ++it)
    t[it][tid] = yraw[(b * 2048 + n0 + it) * 256 + tid];
  __syncthreads();
  int nsub = tid & 63, cq = tid >> 6;
  for (int it = 0; it < 64; ++it) {
    int c = (it << 2) + cq;
    float v = coef2[c] * t[nsub][c] + coef2[256 + c];
    out[(b * 256 + c) * 2048 + n0 + nsub] = v > 0.f ? v : 0.f;
  }
}

extern "C" void kernel_launch(void* const* d_in, const int* in_sizes, int n_in,
                              void* d_out, int out_size, void* d_ws, size_t ws_size,
                              hipStream_t stream) {
  const float* x   = (const float*)d_in[0];
  const float* w1  = (const float*)d_in[1];
  const float* g1  = (const float*)d_in[3];
  const float* be1 = (const float*)d_in[4];
  const float* w2  = (const float*)d_in[5];
  const float* g2  = (const float*)d_in[7];
  const float* be2 = (const float*)d_in[8];
  float* out = (float*)d_out;
  char* w = (char*)d_ws;
  // workspace layout (~106.6 MB total)
  float* sqf    = (float*)(w);                 // 16384 * 4 (slot 131072 B)
  int*  idxbuf  = (int*)(w + 131072);          // 327680 * 4     = 1310720
  uint* hu      = (uint*)(w + 1441792);        // h bf16: 83886080 B
  float* xtf    = (float*)(w + 1441792);       // fp32 xT, 8 MB — ALIASES hu:
                                               // used only in knn (before conv1)
  float* yraw   = (float*)(w + 85327872);      // 4194304 * 4    = 16777216
  float* stats  = (float*)(w + 102105088);     // 4 * 256 floats
  float* coef   = (float*)(w + 102109184);     // 4 * 256 floats
  ushort* wp1   = (ushort*)(w + 102113280);    // 196608 * 2 = 393216
  ushort* wpack = (ushort*)(w + 102506496);    // 999424 * 2 = 1998848
  ushort* xbf_t = (ushort*)(w + 104505344);    // 1048576 * 2 -> end 106602496

  hipMemsetAsync(stats, 0, 4096, stream);
  prep_weights<<<4672, 256, 0, stream>>>(w1, w2, wp1, wpack);
  transpose_x<<<256, 256, 0, stream>>>(x, (uint*)xbf_t, xtf, sqf);
  knn_kernel<<<1024, 1024, 0, stream>>>(xtf, xbf_t, sqf, idxbuf);
  conv1_mfma<<<1024, 256, 0, stream>>>(xbf_t, idxbuf, wp1, hu);
  stats1_kernel<<<1024, 256, 0, stream>>>(hu, stats);
  finalize_kernel<<<1, 256, 0, stream>>>(stats, g1, be1, coef, 1.f / 163840.f);
  conv2_mfma<<<256, 512, 0, stream>>>(xbf_t, idxbuf, hu, coef, wpack, yraw);
  stats2_kernel<<<1024, 256, 0, stream>>>(yraw, stats + 512);
  finalize_kernel<<<1, 256, 0, stream>>>(stats + 512, g2, be2, coef + 512, 1.f / 16384.f);
  out_kernel<<<256, 256, 0, stream>>>(yraw, coef + 512, out);
}

// Round 14
// 401.064 us; speedup vs baseline: 1.3115x; 1.1251x over previous
//
#include <hip/hip_runtime.h>
#include <stdint.h>

typedef unsigned int uint;
typedef unsigned short ushort;
typedef __attribute__((ext_vector_type(8))) short short8;
typedef __attribute__((ext_vector_type(4))) float f32x4;

__device__ __forceinline__ uint f2bf(float f) {
  uint u = __float_as_uint(f);
  return (u + 0x7fffu + ((u >> 16) & 1u)) >> 16;
}
__device__ __forceinline__ float bf2f(uint us) {
  return __uint_as_float(us << 16);
}

// ---------------- weight preprocessing ----------------
// w1: (256, 128, 1, 11)  w2: (256, 128, 1, 40)
// wp1 (bf16): [t(11)][c(256)][d(64)] = w1[c][64+d][t]; then U block at
//   180224 + c*64 + d = sum_t (w1[c][d][t] - w1[c][64+d][t])
// wpack (bf16): conv2 GEMM B in per-fragment-contiguous layout:
//   gp = (((kb*2+ks)*16 + ctile)*64 + lane)*8 + j
//   c  = ctile*16 + (lane&15),  k = kb*64 + ks*32 + (lane>>4)*8 + j
__global__ __launch_bounds__(256) void prep_weights(
    const float* __restrict__ w1, const float* __restrict__ w2,
    ushort* __restrict__ wp1, ushort* __restrict__ wpack) {
  int g = blockIdx.x * 256 + threadIdx.x;
  if (g < 180224) {
    int t = g >> 14;
    int r = g & 16383;
    int c = r >> 6, d = r & 63;
    wp1[g] = (ushort)f2bf(w1[c * 1408 + (64 + d) * 11 + t]);
  } else if (g < 196608) {
    int q = g - 180224;
    int c = q >> 6, d = q & 63;
    float s = 0.f;
    for (int t = 0; t < 11; ++t)
      s += w1[c * 1408 + d * 11 + t] - w1[c * 1408 + (64 + d) * 11 + t];
    wp1[g] = (ushort)f2bf(s);
  } else {
    int gp = g - 196608;            // < 999424 = 61*16384
    int chunk = gp >> 9;            // (kb*2+ks)*16 + ctile
    int r = gp & 511;
    int lane = r >> 3, j = r & 7;
    int kb = chunk >> 5;
    int rem = chunk & 31;
    int ks = rem >> 4, ctile = rem & 15;
    int c = ctile * 16 + (lane & 15);
    int k = kb * 64 + ks * 32 + ((lane >> 4) << 3) + j;
    float val;
    if (k < 64) {
      int d = k;
      float s = 0.f;
      for (int jn = 0; jn < 20; ++jn)
        s += w2[c * 5120 + d * 40 + jn] - w2[c * 5120 + (64 + d) * 40 + jn];
      val = s;
    } else if (k < 1344) {
      int q = k - 64; int jn = q >> 6, d = q & 63;
      val = w2[c * 5120 + (64 + d) * 40 + jn];
    } else {
      int q = k - 1344; int ci = q / 20, jj = q - ci * 20;
      val = w2[c * 5120 + ci * 40 + 20 + jj];
    }
    wpack[gp] = (ushort)f2bf(val);
  }
}

// ---------------- x transpose: bf16 [b][n][d] + fp32 [b][n][d] + sqnorm ----------------
__global__ __launch_bounds__(256) void transpose_x(const float* __restrict__ x,
                                                   uint* __restrict__ xtu,
                                                   float* __restrict__ xtf,
                                                   float* __restrict__ sqf) {
  __shared__ float t[64][65];
  int tid = threadIdx.x;
  int blk = blockIdx.x;            // 256 = 8 b x 32 n-tiles
  int b = blk >> 5, n0 = (blk & 31) << 6;
  const float* xb = x + b * 131072;
  #pragma unroll
  for (int it = 0; it < 16; ++it) {
    int d = (it << 2) + (tid >> 6);
    int n = tid & 63;
    t[d][n] = xb[d * 2048 + n0 + n];
  }
  __syncthreads();
  #pragma unroll
  for (int it = 0; it < 8; ++it) {
    int n = (it << 3) + (tid >> 5);
    int dp = tid & 31;
    float f0 = t[2 * dp][n], f1 = t[2 * dp + 1][n];
    uint v = f2bf(f0) | (f2bf(f1) << 16);
    size_t col = (size_t)(b * 2048 + n0 + n);
    xtu[col * 32 + dp] = v;
    float2 fv; fv.x = f0; fv.y = f1;
    *(float2*)&xtf[(col << 6) + 2 * dp] = fv;
    float s = f0 * f0 + f1 * f1;
    #pragma unroll
    for (int off = 16; off > 0; off >>= 1) s += __shfl_xor(s, off);
    if (dp == 0) sqf[col] = s;
  }
}

// ---------------- kNN v8: column-split halves, 64-KB LDS (2 blocks/CU) ----------------
// Block = 16 rows x 1024 cols (half = blockIdx&1). MFMA dists -> packed keys
// (sortable_fp32 & ~0x7FF) | global_col. 2-winner butterfly x 16 rounds ->
// top-32 superset of the half, written to cbuf[row][half*32..]. Margin: any
// true top-21 neighbor is rank<=21 within its half; 32 >> 21+bf16 noise.
__global__ __launch_bounds__(1024) void knn_kernel(
    const ushort* __restrict__ xbf_t, const float* __restrict__ sqf,
    int* __restrict__ cbuf) {
  __shared__ uint dist[16][1024];   // 64 KB
  int tid = threadIdx.x;
  int wv = tid >> 6, lane = tid & 63;
  int grp = blockIdx.x >> 1;
  int half = blockIdx.x & 1;
  int cbase = half << 10;
  int row0 = grp << 4;
  int b = row0 >> 11, n0 = row0 & 2047;
  const ushort* xt = xbf_t + ((size_t)b << 17);
  const float* sqb = sqf + (b << 11);
  int m = lane & 15, quad = lane >> 4;
  short8 afr0 = *(const short8*)(xt + ((size_t)(n0 + m) << 6) + quad * 8);
  short8 afr1 = *(const short8*)(xt + ((size_t)(n0 + m) << 6) + 32 + quad * 8);
  // phase 1: wave wv computes col-tiles [wv*4, wv*4+4) of this half
  for (int t = 0; t < 4; ++t) {
    int lcol = (((wv << 2) + t) << 4) + m;
    int col = cbase + lcol;
    short8 bfr0 = *(const short8*)(xt + ((size_t)col << 6) + quad * 8);
    short8 bfr1 = *(const short8*)(xt + ((size_t)col << 6) + 32 + quad * 8);
    f32x4 c = {};
    c = __builtin_amdgcn_mfma_f32_16x16x32_bf16(afr0, bfr0, c, 0, 0, 0);
    c = __builtin_amdgcn_mfma_f32_16x16x32_bf16(afr1, bfr1, c, 0, 0, 0);
    float sq = sqb[col];
    #pragma unroll
    for (int r = 0; r < 4; ++r) {
      float f = sq - 2.f * c[r];
      uint u = __float_as_uint(f);
      uint srt = u ^ ((uint)((int)u >> 31) | 0x80000000u);
      dist[quad * 4 + r][lcol] = (srt & 0xFFFFF800u) | (uint)col;
    }
  }
  __syncthreads();
  uint* dr = dist[wv];
  int selfl = (n0 + wv) - cbase;
  if (selfl >= 0 && selfl < 1024 && ((selfl & 63) == lane))
    dr[selfl] = 0xFFFFFFFFu;  // kill self if it lives in this half
  // per-lane sorted top-6 over 16-elem strip: lcol = (l<<6)+lane
  uint v0, v1, v2, v3, v4, v5;
  auto scan6 = [&]() {
    v0 = v1 = v2 = v3 = v4 = v5 = 0xFFFFFFFFu;
    #pragma unroll
    for (int l = 0; l < 16; ++l) {
      uint v = dr[(l << 6) + lane];
      uint t0 = v0 > v ? v0 : v;   v0 = v0 < v ? v0 : v;
      uint t1 = v1 > t0 ? v1 : t0; v1 = v1 < t0 ? v1 : t0;
      uint t2 = v2 > t1 ? v2 : t1; v2 = v2 < t1 ? v2 : t1;
      uint t3 = v3 > t2 ? v3 : t2; v3 = v3 < t2 ? v3 : t2;
      uint t4 = v4 > t3 ? v4 : t3; v4 = v4 < t3 ? v4 : t3;
      v5 = v5 < t4 ? v5 : t4;
    }
  };
  scan6();
  int outb = (row0 + wv) * 64 + (half << 5);
  for (int round = 0; round < 16; ++round) {
    uint w0 = v0, w1 = v1;
    #pragma unroll
    for (int off = 32; off > 0; off >>= 1) {
      uint o0 = (uint)__shfl_xor((int)w0, off);
      uint o1 = (uint)__shfl_xor((int)w1, off);
      uint lo = w0 < o0 ? w0 : o0;
      uint hi = w0 < o0 ? o0 : w0;
      uint mn1 = w1 < o1 ? w1 : o1;
      w0 = lo;
      w1 = hi < mn1 ? hi : mn1;
    }
    if (lane == 0) {
      cbuf[outb + 2 * round] = (int)(w0 & 2047u);
      cbuf[outb + 2 * round + 1] = (int)(w1 & 2047u);
    }
    int own0 = ((w0 & 63u) == (uint)lane) ? 1 : 0;
    int own1 = ((w1 & 63u) == (uint)lane) ? 1 : 0;
    if (own0) dr[(w0 & 2047u) & 1023u] = 0xFFFFFFFFu;
    if (own1) dr[(w1 & 2047u) & 1023u] = 0xFFFFFFFFu;
    int cnt = own0 + own1;
    if (cnt == 1) { v0 = v1; v1 = v2; v2 = v3; v3 = v4; v4 = v5; v5 = 0xFFFFFFFFu; }
    else if (cnt == 2) { v0 = v2; v1 = v3; v2 = v4; v3 = v5; v4 = 0xFFFFFFFFu; v5 = 0xFFFFFFFFu; }
    if (v1 == 0xFFFFFFFFu) scan6();
  }
}

// ---------------- kNN merge: fp64 exact re-rank of 64 candidates/row ----------------
// Wave per row, lane per candidate. Halves are disjoint -> no duplicates.
__global__ __launch_bounds__(256) void knn_merge(
    const float* __restrict__ xtf, const int* __restrict__ cbuf,
    int* __restrict__ idxout) {
  __shared__ double dkey[4][64];
  __shared__ int ccol[4][64];
  int tid = threadIdx.x;
  int wv = tid >> 6, lane = tid & 63;
  int row = (blockIdx.x << 2) + wv;
  int b = row >> 11, n = row & 2047;
  int ci = cbuf[row * 64 + lane];
  const float* xc = xtf + ((size_t)b << 17);
  const float4* xj4 = (const float4*)(xc + ((size_t)ci << 6));
  const float4* xi4 = (const float4*)(xc + ((size_t)n << 6));
  double dt = 0.0, s2 = 0.0;
  #pragma unroll 4
  for (int d4 = 0; d4 < 16; ++d4) {
    float4 vj = xj4[d4];
    float4 vi = xi4[d4];
    double a0 = (double)vj.x, a1 = (double)vj.y, a2 = (double)vj.z, a3 = (double)vj.w;
    s2 += a0 * a0 + a1 * a1 + a2 * a2 + a3 * a3;
    dt += (double)vi.x * a0 + (double)vi.y * a1 + (double)vi.z * a2 + (double)vi.w * a3;
  }
  dkey[wv][lane] = s2 - 2.0 * dt;
  ccol[wv][lane] = ci;
  __syncthreads();
  double kl = dkey[wv][lane];
  int rank = 0;
  for (int mm = 0; mm < 64; ++mm) {
    double km = dkey[wv][mm];
    int cm = ccol[wv][mm];
    if (km < kl || (km == kl && cm < ci)) ++rank;
  }
  if (rank < 20) idxout[row * 20 + rank] = ci;
}

// ---------------- conv1 as bf16 MFMA (tap decomposition, fused BN1 stats) ----------------
// Block: 16 points x 256 channels; slices staged ONCE, channel halves looped.
// Epilogue accumulates per-channel sum/sumsq (quad-shuffle reduce; each
// (wave,m,ct,cg2) owns a unique channel) -> one atomicAdd pair per channel.
__global__ __launch_bounds__(256) void conv1_mfma(
    const ushort* __restrict__ xbf_t, const int* __restrict__ idxbuf,
    const ushort* __restrict__ wp1, uint* __restrict__ hu,
    float* __restrict__ stats) {
  __shared__ ushort sl[21][16][72];   // 48384 B
  __shared__ int nidx[16][20];
  int tid = threadIdx.x;
  int p0 = blockIdx.x << 4;
  int b = p0 >> 11, n0 = p0 & 2047;
  const ushort* xt = xbf_t + ((size_t)b << 17);
  for (int v = tid; v < 320; v += 256) {
    int p = v / 20, j = v - p * 20;
    nidx[p][j] = idxbuf[(p0 + p) * 20 + j];
  }
  __syncthreads();
  for (int v = tid; v < 2688; v += 256) {
    int s = v >> 7;
    int r = v & 127;
    int p = r >> 3, i = r & 7;
    int col = (s == 0) ? (n0 + p) : nidx[p][s - 1];
    *(short8*)&sl[s][p][i << 3] =
        *(const short8*)(xt + ((size_t)col << 6) + (i << 3));
  }
  __syncthreads();
  int lane = tid & 63, wave = tid >> 6;
  int m = lane & 15, quad = lane >> 4;
  #pragma unroll 1
  for (int cg2 = 0; cg2 < 2; ++cg2) {
    int ch0 = (cg2 << 7) + (wave << 4) + m;    // + ct*64
    f32x4 acc[10][2] = {};
    f32x4 cacc[2] = {};
    {
      short8 a0 = *(const short8*)&sl[0][m][quad * 8];
      short8 a1 = *(const short8*)&sl[0][m][32 + quad * 8];
      #pragma unroll
      for (int ct = 0; ct < 2; ++ct) {
        const ushort* urow = wp1 + 180224 + (ch0 + ct * 64) * 64 + quad * 8;
        short8 b0 = *(const short8*)(urow);
        short8 b1 = *(const short8*)(urow + 32);
        cacc[ct] = __builtin_amdgcn_mfma_f32_16x16x32_bf16(a0, b0, cacc[ct], 0, 0, 0);
        cacc[ct] = __builtin_amdgcn_mfma_f32_16x16x32_bf16(a1, b1, cacc[ct], 0, 0, 0);
      }
    }
    #pragma unroll
    for (int t = 0; t < 11; ++t) {
      short8 b0[2], b1[2];
      #pragma unroll
      for (int ct = 0; ct < 2; ++ct) {
        const ushort* brow = wp1 + t * 16384 + (ch0 + ct * 64) * 64 + quad * 8;
        b0[ct] = *(const short8*)(brow);
        b1[ct] = *(const short8*)(brow + 32);
      }
      #pragma unroll
      for (int ko = 0; ko < 10; ++ko) {
        int s = 1 + ko + t;
        short8 a0 = *(const short8*)&sl[s][m][quad * 8];
        short8 a1 = *(const short8*)&sl[s][m][32 + quad * 8];
        #pragma unroll
        for (int ct = 0; ct < 2; ++ct) {
          acc[ko][ct] = __builtin_amdgcn_mfma_f32_16x16x32_bf16(a0, b0[ct], acc[ko][ct], 0, 0, 0);
          acc[ko][ct] = __builtin_amdgcn_mfma_f32_16x16x32_bf16(a1, b1[ct], acc[ko][ct], 0, 0, 0);
        }
      }
    }
    #pragma unroll
    for (int ct = 0; ct < 2; ++ct) {
      int c = ch0 + ct * 64;
      float sacc = 0.f, ssacc = 0.f;
      #pragma unroll
      for (int r = 0; r < 4; ++r) {
        int p = (quad << 2) + r;
        int base5 = ((p0 + p) * 256 + c) * 5;
        float cc = cacc[ct][r];
        #pragma unroll
        for (int q = 0; q < 5; ++q) {
          float f0 = acc[2 * q][ct][r] + cc;
          float f1 = acc[2 * q + 1][ct][r] + cc;
          sacc += f0 + f1;
          ssacc += f0 * f0 + f1 * f1;
          hu[base5 + q] = f2bf(f0) | (f2bf(f1) << 16);
        }
      }
      sacc += __shfl_xor(sacc, 16);  sacc += __shfl_xor(sacc, 32);
      ssacc += __shfl_xor(ssacc, 16); ssacc += __shfl_xor(ssacc, 32);
      if (quad == 0) {
        atomicAdd(&stats[c], sacc);
        atomicAdd(&stats[256 + c], ssacc);
      }
    }
  }
}

__global__ void finalize_kernel(const float* __restrict__ stats,
                                const float* __restrict__ gamma,
                                const float* __restrict__ beta,
                                float* __restrict__ coef, float inv_count) {
  int c = threadIdx.x;
  float m = stats[c] * inv_count;
  float var = stats[256 + c] * inv_count - m * m;
  float a = gamma[c] * rsqrtf(var + 1e-5f);
  coef[c] = a;
  coef[256 + c] = beta[c] - m * a;
}

// ---------------- conv2 as bf16 MFMA GEMM v3 (fused BN2 stats) ----------------
// Block: 64 points x 256 ch, 512 threads (8 waves x 32 ch), 256 blocks = 1/CU.
__global__ __launch_bounds__(512) void conv2_mfma(
    const ushort* __restrict__ xbf_t, const int* __restrict__ idxbuf,
    const uint* __restrict__ hu, const float* __restrict__ coef1,
    const ushort* __restrict__ wpack, float* __restrict__ yraw,
    float* __restrict__ stats) {
  __shared__ ushort As[2][4][64][72];   // 73728 B
  __shared__ int nidx[64][20];
  __shared__ float cf[512];
  int tid = threadIdx.x;
  int p0 = blockIdx.x << 6;          // 64 points per block
  int b = p0 >> 11, n0 = p0 & 2047;
  const ushort* xt = xbf_t + ((size_t)b << 17);

  cf[tid] = coef1[tid];
  for (int v = tid; v < 1280; v += 512) {
    int p = v / 20, j = v - p * 20;
    nidx[p][j] = idxbuf[(p0 + p) * 20 + j];
  }
  __syncthreads();

  int pp = tid >> 3;                 // point 0..63
  int off = (tid & 7) << 3;          // 8-col chunk within 64

  auto build = [&](int phase, int buf) {
    int kb0 = phase << 2;
    short8 xv[4];
    uint4 hv[4];
    #pragma unroll
    for (int kc = 0; kc < 4; ++kc) {
      int kb = kb0 + kc;
      if (kb >= 61) continue;
      if (kb < 21) {
        int col = (kb == 0) ? (n0 + pp) : nidx[pp][kb - 1];
        xv[kc] = *(const short8*)(xt + ((size_t)col << 6) + off);
      } else {
        int q0 = (kb - 21) * 64 + off;
        hv[kc] = *(const uint4*)(hu + (size_t)(p0 + pp) * 1280 + (q0 >> 1));
      }
    }
    #pragma unroll
    for (int kc = 0; kc < 4; ++kc) {
      int kb = kb0 + kc;
      if (kb >= 61) continue;
      if (kb < 21) {
        *(short8*)&As[buf][kc][pp][off] = xv[kc];
      } else {
        int q0 = (kb - 21) * 64 + off;
        uint4 hvv = hv[kc];
        float f[8];
        f[0] = bf2f(hvv.x & 0xffffu); f[1] = bf2f(hvv.x >> 16);
        f[2] = bf2f(hvv.y & 0xffffu); f[3] = bf2f(hvv.y >> 16);
        f[4] = bf2f(hvv.z & 0xffffu); f[5] = bf2f(hvv.z >> 16);
        f[6] = bf2f(hvv.w & 0xffffu); f[7] = bf2f(hvv.w >> 16);
        ushort o[8];
        #pragma unroll
        for (int i = 0; i < 8; ++i) {
          int ch = (q0 + i) / 10;
          float vv = f[i] * cf[ch] + cf[256 + ch];
          vv = vv > 0.f ? vv : 0.01f * vv;
          o[i] = (ushort)f2bf(vv);
        }
        *(short8*)&As[buf][kc][pp][off] = *(short8*)o;
      }
    }
  };

  int lane = tid & 63, wave = tid >> 6;
  int m = lane & 15, quad = lane >> 4;
  f32x4 acc[4][2] = {};

  build(0, 0);
  __syncthreads();
  for (int phase = 0; phase < 16; ++phase) {
    int buf = phase & 1;
    if (phase < 15) build(phase + 1, buf ^ 1);
    #pragma unroll
    for (int kc = 0; kc < 4; ++kc) {
      int kb = (phase << 2) + kc;
      if (kb >= 61) break;
      #pragma unroll
      for (int ks = 0; ks < 2; ++ks) {
        short8 afr[4];
        #pragma unroll
        for (int mt = 0; mt < 4; ++mt)
          afr[mt] = *(const short8*)&As[buf][kc][mt * 16 + m][ks * 32 + quad * 8];
        #pragma unroll
        for (int nt = 0; nt < 2; ++nt) {
          const ushort* bp = wpack +
              (((size_t)((kb * 2 + ks) * 16 + (wave << 1) + nt)) << 9) + lane * 8;
          short8 bfr = *(const short8*)bp;
          #pragma unroll
          for (int mt = 0; mt < 4; ++mt)
            acc[mt][nt] = __builtin_amdgcn_mfma_f32_16x16x32_bf16(afr[mt], bfr, acc[mt][nt], 0, 0, 0);
        }
      }
    }
    __syncthreads();
  }
  // epilogue: D col=lane&15 -> channel, row=quad*4+r -> point; fused stats
  #pragma unroll
  for (int nt = 0; nt < 2; ++nt) {
    int col = (wave << 5) + nt * 16 + m;
    float sacc = 0.f, ssacc = 0.f;
    #pragma unroll
    for (int mt = 0; mt < 4; ++mt) {
      #pragma unroll
      for (int r = 0; r < 4; ++r) {
        int prow = mt * 16 + quad * 4 + r;
        float v = acc[mt][nt][r];
        sacc += v; ssacc += v * v;
        yraw[(size_t)(p0 + prow) * 256 + col] = v;
      }
    }
    sacc += __shfl_xor(sacc, 16);  sacc += __shfl_xor(sacc, 32);
    ssacc += __shfl_xor(ssacc, 16); ssacc += __shfl_xor(ssacc, 32);
    if (quad == 0) {
      atomicAdd(&stats[col], sacc);
      atomicAdd(&stats[256 + col], ssacc);
    }
  }
}

// ---------------- BN2 + relu + transpose to (b, c, n) ----------------
__global__ __launch_bounds__(256) void out_kernel(const float* __restrict__ yraw,
                                                  const float* __restrict__ coef2,
                                                  float* __restrict__ out) {
  __shared__ float t[64][257];
  int tid = threadIdx.x;
  int blk = blockIdx.x;            // 256 = 8 b x 32 n-tiles
  int b = blk >> 5, n0 = (blk & 31) << 6;
  for (int it = 0; it < 64; ++it)
    t[it][tid] = yraw[(b * 2048 + n0 + it) * 256 + tid];
  __syncthreads();
  int nsub = tid & 63, cq = tid >> 6;
  for (int it = 0; it < 64; ++it) {
    int c = (it << 2) + cq;
    float v = coef2[c] * t[nsub][c] + coef2[256 + c];
    out[(b * 256 + c) * 2048 + n0 + nsub] = v > 0.f ? v : 0.f;
  }
}

extern "C" void kernel_launch(void* const* d_in, const int* in_sizes, int n_in,
                              void* d_out, int out_size, void* d_ws, size_t ws_size,
                              hipStream_t stream) {
  const float* x   = (const float*)d_in[0];
  const float* w1  = (const float*)d_in[1];
  const float* g1  = (const float*)d_in[3];
  const float* be1 = (const float*)d_in[4];
  const float* w2  = (const float*)d_in[5];
  const float* g2  = (const float*)d_in[7];
  const float* be2 = (const float*)d_in[8];
  float* out = (float*)d_out;
  char* w = (char*)d_ws;
  // workspace layout (~106.6 MB total)
  float* sqf    = (float*)(w);                 // 16384 * 4 (slot 131072 B)
  int*  idxbuf  = (int*)(w + 131072);          // 327680 * 4     = 1310720
  uint* hu      = (uint*)(w + 1441792);        // h bf16: 83886080 B
  float* xtf    = (float*)(w + 1441792);       // fp32 xT, 8 MB — ALIASES hu
  int*  cbuf    = (int*)(w + 9830400);         // 16384*64*4 = 4 MB — ALIASES hu
                                               // (xtf/cbuf dead before conv1)
  float* yraw   = (float*)(w + 85327872);      // 4194304 * 4    = 16777216
  float* stats  = (float*)(w + 102105088);     // 4 * 256 floats
  float* coef   = (float*)(w + 102109184);     // 4 * 256 floats
  ushort* wp1   = (ushort*)(w + 102113280);    // 196608 * 2 = 393216
  ushort* wpack = (ushort*)(w + 102506496);    // 999424 * 2 = 1998848
  ushort* xbf_t = (ushort*)(w + 104505344);    // 1048576 * 2 -> end 106602496

  hipMemsetAsync(stats, 0, 4096, stream);
  prep_weights<<<4672, 256, 0, stream>>>(w1, w2, wp1, wpack);
  transpose_x<<<256, 256, 0, stream>>>(x, (uint*)xbf_t, xtf, sqf);
  knn_kernel<<<2048, 1024, 0, stream>>>(xbf_t, sqf, cbuf);
  knn_merge<<<4096, 256, 0, stream>>>(xtf, cbuf, idxbuf);
  conv1_mfma<<<1024, 256, 0, stream>>>(xbf_t, idxbuf, wp1, hu, stats);
  finalize_kernel<<<1, 256, 0, stream>>>(stats, g1, be1, coef, 1.f / 163840.f);
  conv2_mfma<<<256, 512, 0, stream>>>(xbf_t, idxbuf, hu, coef, wpack, yraw, stats + 512);
  finalize_kernel<<<1, 256, 0, stream>>>(stats + 512, g2, be2, coef + 512, 1.f / 16384.f);
  out_kernel<<<256, 256, 0, stream>>>(yraw, coef + 512, out);
}

// Round 15
// 385.960 us; speedup vs baseline: 1.3628x; 1.0391x over previous
//
#include <hip/hip_runtime.h>
#include <stdint.h>

typedef unsigned int uint;
typedef unsigned short ushort;
typedef __attribute__((ext_vector_type(8))) short short8;
typedef __attribute__((ext_vector_type(4))) float f32x4;

__device__ __forceinline__ uint f2bf(float f) {
  uint u = __float_as_uint(f);
  return (u + 0x7fffu + ((u >> 16) & 1u)) >> 16;
}
__device__ __forceinline__ float bf2f(uint us) {
  return __uint_as_float(us << 16);
}

// ---------------- weight preprocessing ----------------
// w1: (256, 128, 1, 11)  w2: (256, 128, 1, 40)
// wp1 (bf16), fragment-contiguous: chunk = (t*2+ks)*16 + ctile, t=0..11
//   (t=11 is the U block); element [chunk][lane][8]:
//   c = ctile*16 + (lane&15), d = ks*32 + (lane>>4)*8 + j
//   t<11: val = w1[c][64+d][t];  t==11: val = sum_t(w1[c][d][t]-w1[c][64+d][t])
// wpack (bf16): conv2 GEMM B fragment-contiguous (unchanged from R12):
//   gp = (((kb*2+ks)*16 + ctile)*64 + lane)*8 + j
__global__ __launch_bounds__(256) void prep_weights(
    const float* __restrict__ w1, const float* __restrict__ w2,
    ushort* __restrict__ wp1, ushort* __restrict__ wpack) {
  int g = blockIdx.x * 256 + threadIdx.x;
  if (g < 196608) {
    int chunk = g >> 9;            // (t*2+ks)*16 + ctile
    int r = g & 511;
    int lane = r >> 3, j = r & 7;
    int tks = chunk >> 4;
    int ctile = chunk & 15;
    int t = tks >> 1, ks = tks & 1;
    int c = ctile * 16 + (lane & 15);
    int d = ks * 32 + ((lane >> 4) << 3) + j;
    float val;
    if (t < 11) {
      val = w1[c * 1408 + (64 + d) * 11 + t];
    } else {
      float s = 0.f;
      for (int tt = 0; tt < 11; ++tt)
        s += w1[c * 1408 + d * 11 + tt] - w1[c * 1408 + (64 + d) * 11 + tt];
      val = s;
    }
    wp1[g] = (ushort)f2bf(val);
  } else {
    int gp = g - 196608;            // < 999424 = 61*16384
    int chunk = gp >> 9;            // (kb*2+ks)*16 + ctile
    int r = gp & 511;
    int lane = r >> 3, j = r & 7;
    int kb = chunk >> 5;
    int rem = chunk & 31;
    int ks = rem >> 4, ctile = rem & 15;
    int c = ctile * 16 + (lane & 15);
    int k = kb * 64 + ks * 32 + ((lane >> 4) << 3) + j;
    float val;
    if (k < 64) {
      int d = k;
      float s = 0.f;
      for (int jn = 0; jn < 20; ++jn)
        s += w2[c * 5120 + d * 40 + jn] - w2[c * 5120 + (64 + d) * 40 + jn];
      val = s;
    } else if (k < 1344) {
      int q = k - 64; int jn = q >> 6, d = q & 63;
      val = w2[c * 5120 + (64 + d) * 40 + jn];
    } else {
      int q = k - 1344; int ci = q / 20, jj = q - ci * 20;
      val = w2[c * 5120 + ci * 40 + 20 + jj];
    }
    wpack[gp] = (ushort)f2bf(val);
  }
}

// ---------------- x transpose: bf16 [b][n][d] + fp32 [b][n][d] + sqnorm ----------------
__global__ __launch_bounds__(256) void transpose_x(const float* __restrict__ x,
                                                   uint* __restrict__ xtu,
                                                   float* __restrict__ xtf,
                                                   float* __restrict__ sqf) {
  __shared__ float t[64][65];
  int tid = threadIdx.x;
  int blk = blockIdx.x;            // 256 = 8 b x 32 n-tiles
  int b = blk >> 5, n0 = (blk & 31) << 6;
  const float* xb = x + b * 131072;
  #pragma unroll
  for (int it = 0; it < 16; ++it) {
    int d = (it << 2) + (tid >> 6);
    int n = tid & 63;
    t[d][n] = xb[d * 2048 + n0 + n];
  }
  __syncthreads();
  #pragma unroll
  for (int it = 0; it < 8; ++it) {
    int n = (it << 3) + (tid >> 5);
    int dp = tid & 31;
    float f0 = t[2 * dp][n], f1 = t[2 * dp + 1][n];
    uint v = f2bf(f0) | (f2bf(f1) << 16);
    size_t col = (size_t)(b * 2048 + n0 + n);
    xtu[col * 32 + dp] = v;
    float2 fv; fv.x = f0; fv.y = f1;
    *(float2*)&xtf[(col << 6) + 2 * dp] = fv;
    float s = f0 * f0 + f1 * f1;
    #pragma unroll
    for (int off = 16; off > 0; off >>= 1) s += __shfl_xor(s, off);
    if (dp == 0) sqf[col] = s;
  }
}

// ---------------- kNN v8: column-split halves, 64-KB LDS (2 blocks/CU) ----------------
__global__ __launch_bounds__(1024) void knn_kernel(
    const ushort* __restrict__ xbf_t, const float* __restrict__ sqf,
    int* __restrict__ cbuf) {
  __shared__ uint dist[16][1024];   // 64 KB
  int tid = threadIdx.x;
  int wv = tid >> 6, lane = tid & 63;
  int grp = blockIdx.x >> 1;
  int half = blockIdx.x & 1;
  int cbase = half << 10;
  int row0 = grp << 4;
  int b = row0 >> 11, n0 = row0 & 2047;
  const ushort* xt = xbf_t + ((size_t)b << 17);
  const float* sqb = sqf + (b << 11);
  int m = lane & 15, quad = lane >> 4;
  short8 afr0 = *(const short8*)(xt + ((size_t)(n0 + m) << 6) + quad * 8);
  short8 afr1 = *(const short8*)(xt + ((size_t)(n0 + m) << 6) + 32 + quad * 8);
  for (int t = 0; t < 4; ++t) {
    int lcol = (((wv << 2) + t) << 4) + m;
    int col = cbase + lcol;
    short8 bfr0 = *(const short8*)(xt + ((size_t)col << 6) + quad * 8);
    short8 bfr1 = *(const short8*)(xt + ((size_t)col << 6) + 32 + quad * 8);
    f32x4 c = {};
    c = __builtin_amdgcn_mfma_f32_16x16x32_bf16(afr0, bfr0, c, 0, 0, 0);
    c = __builtin_amdgcn_mfma_f32_16x16x32_bf16(afr1, bfr1, c, 0, 0, 0);
    float sq = sqb[col];
    #pragma unroll
    for (int r = 0; r < 4; ++r) {
      float f = sq - 2.f * c[r];
      uint u = __float_as_uint(f);
      uint srt = u ^ ((uint)((int)u >> 31) | 0x80000000u);
      dist[quad * 4 + r][lcol] = (srt & 0xFFFFF800u) | (uint)col;
    }
  }
  __syncthreads();
  uint* dr = dist[wv];
  int selfl = (n0 + wv) - cbase;
  if (selfl >= 0 && selfl < 1024 && ((selfl & 63) == lane))
    dr[selfl] = 0xFFFFFFFFu;
  uint v0, v1, v2, v3, v4, v5;
  auto scan6 = [&]() {
    v0 = v1 = v2 = v3 = v4 = v5 = 0xFFFFFFFFu;
    #pragma unroll
    for (int l = 0; l < 16; ++l) {
      uint v = dr[(l << 6) + lane];
      uint t0 = v0 > v ? v0 : v;   v0 = v0 < v ? v0 : v;
      uint t1 = v1 > t0 ? v1 : t0; v1 = v1 < t0 ? v1 : t0;
      uint t2 = v2 > t1 ? v2 : t1; v2 = v2 < t1 ? v2 : t1;
      uint t3 = v3 > t2 ? v3 : t2; v3 = v3 < t2 ? v3 : t2;
      uint t4 = v4 > t3 ? v4 : t3; v4 = v4 < t3 ? v4 : t3;
      v5 = v5 < t4 ? v5 : t4;
    }
  };
  scan6();
  int outb = (row0 + wv) * 64 + (half << 5);
  for (int round = 0; round < 16; ++round) {
    uint w0 = v0, w1 = v1;
    #pragma unroll
    for (int off = 32; off > 0; off >>= 1) {
      uint o0 = (uint)__shfl_xor((int)w0, off);
      uint o1 = (uint)__shfl_xor((int)w1, off);
      uint lo = w0 < o0 ? w0 : o0;
      uint hi = w0 < o0 ? o0 : w0;
      uint mn1 = w1 < o1 ? w1 : o1;
      w0 = lo;
      w1 = hi < mn1 ? hi : mn1;
    }
    if (lane == 0) {
      cbuf[outb + 2 * round] = (int)(w0 & 2047u);
      cbuf[outb + 2 * round + 1] = (int)(w1 & 2047u);
    }
    int own0 = ((w0 & 63u) == (uint)lane) ? 1 : 0;
    int own1 = ((w1 & 63u) == (uint)lane) ? 1 : 0;
    if (own0) dr[(w0 & 2047u) & 1023u] = 0xFFFFFFFFu;
    if (own1) dr[(w1 & 2047u) & 1023u] = 0xFFFFFFFFu;
    int cnt = own0 + own1;
    if (cnt == 1) { v0 = v1; v1 = v2; v2 = v3; v3 = v4; v4 = v5; v5 = 0xFFFFFFFFu; }
    else if (cnt == 2) { v0 = v2; v1 = v3; v2 = v4; v3 = v5; v4 = 0xFFFFFFFFu; v5 = 0xFFFFFFFFu; }
    if (v1 == 0xFFFFFFFFu) scan6();
  }
}

// ---------------- kNN merge: fp64 exact re-rank of 64 candidates/row ----------------
__global__ __launch_bounds__(256) void knn_merge(
    const float* __restrict__ xtf, const int* __restrict__ cbuf,
    int* __restrict__ idxout) {
  __shared__ double dkey[4][64];
  __shared__ int ccol[4][64];
  int tid = threadIdx.x;
  int wv = tid >> 6, lane = tid & 63;
  int row = (blockIdx.x << 2) + wv;
  int b = row >> 11, n = row & 2047;
  int ci = cbuf[row * 64 + lane];
  const float* xc = xtf + ((size_t)b << 17);
  const float4* xj4 = (const float4*)(xc + ((size_t)ci << 6));
  const float4* xi4 = (const float4*)(xc + ((size_t)n << 6));
  double dt = 0.0, s2 = 0.0;
  #pragma unroll 4
  for (int d4 = 0; d4 < 16; ++d4) {
    float4 vj = xj4[d4];
    float4 vi = xi4[d4];
    double a0 = (double)vj.x, a1 = (double)vj.y, a2 = (double)vj.z, a3 = (double)vj.w;
    s2 += a0 * a0 + a1 * a1 + a2 * a2 + a3 * a3;
    dt += (double)vi.x * a0 + (double)vi.y * a1 + (double)vi.z * a2 + (double)vi.w * a3;
  }
  dkey[wv][lane] = s2 - 2.0 * dt;
  ccol[wv][lane] = ci;
  __syncthreads();
  double kl = dkey[wv][lane];
  int rank = 0;
  for (int mm = 0; mm < 64; ++mm) {
    double km = dkey[wv][mm];
    int cm = ccol[wv][mm];
    if (km < kl || (km == kl && cm < ci)) ++rank;
  }
  if (rank < 20) idxout[row * 20 + rank] = ci;
}

// ---------------- conv1 as bf16 MFMA v2: ko-split (6+4) for VGPR<=128,
// fragment-contiguous wp1 B-loads, fused BN1 stats ----------------
// Block: 16 points x 256 channels (4 waves x 2 ct x 2 cg2).
__global__ __launch_bounds__(256, 4) void conv1_mfma(
    const ushort* __restrict__ xbf_t, const int* __restrict__ idxbuf,
    const ushort* __restrict__ wp1, uint* __restrict__ hu,
    float* __restrict__ stats) {
  __shared__ ushort sl[21][16][72];   // 48384 B
  __shared__ int nidx[16][20];
  int tid = threadIdx.x;
  int p0 = blockIdx.x << 4;
  int b = p0 >> 11, n0 = p0 & 2047;
  const ushort* xt = xbf_t + ((size_t)b << 17);
  for (int v = tid; v < 320; v += 256) {
    int p = v / 20, j = v - p * 20;
    nidx[p][j] = idxbuf[(p0 + p) * 20 + j];
  }
  __syncthreads();
  for (int v = tid; v < 2688; v += 256) {
    int s = v >> 7;
    int r = v & 127;
    int p = r >> 3, i = r & 7;
    int col = (s == 0) ? (n0 + p) : nidx[p][s - 1];
    *(short8*)&sl[s][p][i << 3] =
        *(const short8*)(xt + ((size_t)col << 6) + (i << 3));
  }
  __syncthreads();
  int lane = tid & 63, wave = tid >> 6;
  int m = lane & 15, quad = lane >> 4;
  #pragma unroll 1
  for (int cg2 = 0; cg2 < 2; ++cg2) {
    int ctb = (cg2 << 3) + wave;
    f32x4 cacc[2] = {};
    float sacc[2] = {0.f, 0.f}, ssacc[2] = {0.f, 0.f};
    {
      short8 a0 = *(const short8*)&sl[0][m][quad * 8];
      short8 a1 = *(const short8*)&sl[0][m][32 + quad * 8];
      #pragma unroll
      for (int ct = 0; ct < 2; ++ct) {
        int ctile = ctb + (ct << 2);
        short8 b0 = *(const short8*)(wp1 + ((22 * 16 + ctile) << 9) + lane * 8);
        short8 b1 = *(const short8*)(wp1 + ((23 * 16 + ctile) << 9) + lane * 8);
        cacc[ct] = __builtin_amdgcn_mfma_f32_16x16x32_bf16(a0, b0, cacc[ct], 0, 0, 0);
        cacc[ct] = __builtin_amdgcn_mfma_f32_16x16x32_bf16(a1, b1, cacc[ct], 0, 0, 0);
      }
    }
    // ---- koh = 0: ko 0..5 -> hu pairs q = 0,1,2
    {
      f32x4 acc[6][2] = {};
      #pragma unroll
      for (int t = 0; t < 11; ++t) {
        short8 b0[2], b1[2];
        #pragma unroll
        for (int ct = 0; ct < 2; ++ct) {
          int ctile = ctb + (ct << 2);
          b0[ct] = *(const short8*)(wp1 + (((t * 2 + 0) * 16 + ctile) << 9) + lane * 8);
          b1[ct] = *(const short8*)(wp1 + (((t * 2 + 1) * 16 + ctile) << 9) + lane * 8);
        }
        #pragma unroll
        for (int ko = 0; ko < 6; ++ko) {
          int s = 1 + ko + t;
          short8 a0 = *(const short8*)&sl[s][m][quad * 8];
          short8 a1 = *(const short8*)&sl[s][m][32 + quad * 8];
          #pragma unroll
          for (int ct = 0; ct < 2; ++ct) {
            acc[ko][ct] = __builtin_amdgcn_mfma_f32_16x16x32_bf16(a0, b0[ct], acc[ko][ct], 0, 0, 0);
            acc[ko][ct] = __builtin_amdgcn_mfma_f32_16x16x32_bf16(a1, b1[ct], acc[ko][ct], 0, 0, 0);
          }
        }
      }
      #pragma unroll
      for (int ct = 0; ct < 2; ++ct) {
        int c = (cg2 << 7) + (ct << 6) + (wave << 4) + m;
        #pragma unroll
        for (int r = 0; r < 4; ++r) {
          int p = (quad << 2) + r;
          int base5 = ((p0 + p) * 256 + c) * 5;
          float cc = cacc[ct][r];
          #pragma unroll
          for (int q = 0; q < 3; ++q) {
            float f0 = acc[2 * q][ct][r] + cc;
            float f1 = acc[2 * q + 1][ct][r] + cc;
            sacc[ct] += f0 + f1;
            ssacc[ct] += f0 * f0 + f1 * f1;
            hu[base5 + q] = f2bf(f0) | (f2bf(f1) << 16);
          }
        }
      }
    }
    // ---- koh = 1: ko 6..9 -> hu pairs q = 3,4
    {
      f32x4 acc[4][2] = {};
      #pragma unroll
      for (int t = 0; t < 11; ++t) {
        short8 b0[2], b1[2];
        #pragma unroll
        for (int ct = 0; ct < 2; ++ct) {
          int ctile = ctb + (ct << 2);
          b0[ct] = *(const short8*)(wp1 + (((t * 2 + 0) * 16 + ctile) << 9) + lane * 8);
          b1[ct] = *(const short8*)(wp1 + (((t * 2 + 1) * 16 + ctile) << 9) + lane * 8);
        }
        #pragma unroll
        for (int ko = 0; ko < 4; ++ko) {
          int s = 7 + ko + t;
          short8 a0 = *(const short8*)&sl[s][m][quad * 8];
          short8 a1 = *(const short8*)&sl[s][m][32 + quad * 8];
          #pragma unroll
          for (int ct = 0; ct < 2; ++ct) {
            acc[ko][ct] = __builtin_amdgcn_mfma_f32_16x16x32_bf16(a0, b0[ct], acc[ko][ct], 0, 0, 0);
            acc[ko][ct] = __builtin_amdgcn_mfma_f32_16x16x32_bf16(a1, b1[ct], acc[ko][ct], 0, 0, 0);
          }
        }
      }
      #pragma unroll
      for (int ct = 0; ct < 2; ++ct) {
        int c = (cg2 << 7) + (ct << 6) + (wave << 4) + m;
        #pragma unroll
        for (int r = 0; r < 4; ++r) {
          int p = (quad << 2) + r;
          int base5 = ((p0 + p) * 256 + c) * 5;
          float cc = cacc[ct][r];
          #pragma unroll
          for (int q = 0; q < 2; ++q) {
            float f0 = acc[2 * q][ct][r] + cc;
            float f1 = acc[2 * q + 1][ct][r] + cc;
            sacc[ct] += f0 + f1;
            ssacc[ct] += f0 * f0 + f1 * f1;
            hu[base5 + 3 + q] = f2bf(f0) | (f2bf(f1) << 16);
          }
        }
      }
    }
    // ---- fused BN1 stats: quad-shuffle reduce, one atomic pair per channel
    #pragma unroll
    for (int ct = 0; ct < 2; ++ct) {
      int c = (cg2 << 7) + (ct << 6) + (wave << 4) + m;
      float sa = sacc[ct], ssa = ssacc[ct];
      sa += __shfl_xor(sa, 16);  sa += __shfl_xor(sa, 32);
      ssa += __shfl_xor(ssa, 16); ssa += __shfl_xor(ssa, 32);
      if (quad == 0) {
        atomicAdd(&stats[c], sa);
        atomicAdd(&stats[256 + c], ssa);
      }
    }
  }
}

__global__ void finalize_kernel(const float* __restrict__ stats,
                                const float* __restrict__ gamma,
                                const float* __restrict__ beta,
                                float* __restrict__ coef, float inv_count) {
  int c = threadIdx.x;
  float m = stats[c] * inv_count;
  float var = stats[256 + c] * inv_count - m * m;
  float a = gamma[c] * rsqrtf(var + 1e-5f);
  coef[c] = a;
  coef[256 + c] = beta[c] - m * a;
}

// ---------------- conv2 as bf16 MFMA GEMM v3 (fused BN2 stats) ----------------
__global__ __launch_bounds__(512) void conv2_mfma(
    const ushort* __restrict__ xbf_t, const int* __restrict__ idxbuf,
    const uint* __restrict__ hu, const float* __restrict__ coef1,
    const ushort* __restrict__ wpack, float* __restrict__ yraw,
    float* __restrict__ stats) {
  __shared__ ushort As[2][4][64][72];   // 73728 B
  __shared__ int nidx[64][20];
  __shared__ float cf[512];
  int tid = threadIdx.x;
  int p0 = blockIdx.x << 6;          // 64 points per block
  int b = p0 >> 11, n0 = p0 & 2047;
  const ushort* xt = xbf_t + ((size_t)b << 17);

  cf[tid] = coef1[tid];
  for (int v = tid; v < 1280; v += 512) {
    int p = v / 20, j = v - p * 20;
    nidx[p][j] = idxbuf[(p0 + p) * 20 + j];
  }
  __syncthreads();

  int pp = tid >> 3;                 // point 0..63
  int off = (tid & 7) << 3;          // 8-col chunk within 64

  auto build = [&](int phase, int buf) {
    int kb0 = phase << 2;
    short8 xv[4];
    uint4 hv[4];
    #pragma unroll
    for (int kc = 0; kc < 4; ++kc) {
      int kb = kb0 + kc;
      if (kb >= 61) continue;
      if (kb < 21) {
        int col = (kb == 0) ? (n0 + pp) : nidx[pp][kb - 1];
        xv[kc] = *(const short8*)(xt + ((size_t)col << 6) + off);
      } else {
        int q0 = (kb - 21) * 64 + off;
        hv[kc] = *(const uint4*)(hu + (size_t)(p0 + pp) * 1280 + (q0 >> 1));
      }
    }
    #pragma unroll
    for (int kc = 0; kc < 4; ++kc) {
      int kb = kb0 + kc;
      if (kb >= 61) continue;
      if (kb < 21) {
        *(short8*)&As[buf][kc][pp][off] = xv[kc];
      } else {
        int q0 = (kb - 21) * 64 + off;
        uint4 hvv = hv[kc];
        float f[8];
        f[0] = bf2f(hvv.x & 0xffffu); f[1] = bf2f(hvv.x >> 16);
        f[2] = bf2f(hvv.y & 0xffffu); f[3] = bf2f(hvv.y >> 16);
        f[4] = bf2f(hvv.z & 0xffffu); f[5] = bf2f(hvv.z >> 16);
        f[6] = bf2f(hvv.w & 0xffffu); f[7] = bf2f(hvv.w >> 16);
        ushort o[8];
        #pragma unroll
        for (int i = 0; i < 8; ++i) {
          int ch = (q0 + i) / 10;
          float vv = f[i] * cf[ch] + cf[256 + ch];
          vv = vv > 0.f ? vv : 0.01f * vv;
          o[i] = (ushort)f2bf(vv);
        }
        *(short8*)&As[buf][kc][pp][off] = *(short8*)o;
      }
    }
  };

  int lane = tid & 63, wave = tid >> 6;
  int m = lane & 15, quad = lane >> 4;
  f32x4 acc[4][2] = {};

  build(0, 0);
  __syncthreads();
  for (int phase = 0; phase < 16; ++phase) {
    int buf = phase & 1;
    if (phase < 15) build(phase + 1, buf ^ 1);
    #pragma unroll
    for (int kc = 0; kc < 4; ++kc) {
      int kb = (phase << 2) + kc;
      if (kb >= 61) break;
      #pragma unroll
      for (int ks = 0; ks < 2; ++ks) {
        short8 afr[4];
        #pragma unroll
        for (int mt = 0; mt < 4; ++mt)
          afr[mt] = *(const short8*)&As[buf][kc][mt * 16 + m][ks * 32 + quad * 8];
        #pragma unroll
        for (int nt = 0; nt < 2; ++nt) {
          const ushort* bp = wpack +
              (((size_t)((kb * 2 + ks) * 16 + (wave << 1) + nt)) << 9) + lane * 8;
          short8 bfr = *(const short8*)bp;
          #pragma unroll
          for (int mt = 0; mt < 4; ++mt)
            acc[mt][nt] = __builtin_amdgcn_mfma_f32_16x16x32_bf16(afr[mt], bfr, acc[mt][nt], 0, 0, 0);
        }
      }
    }
    __syncthreads();
  }
  #pragma unroll
  for (int nt = 0; nt < 2; ++nt) {
    int col = (wave << 5) + nt * 16 + m;
    float sacc = 0.f, ssacc = 0.f;
    #pragma unroll
    for (int mt = 0; mt < 4; ++mt) {
      #pragma unroll
      for (int r = 0; r < 4; ++r) {
        int prow = mt * 16 + quad * 4 + r;
        float v = acc[mt][nt][r];
        sacc += v; ssacc += v * v;
        yraw[(size_t)(p0 + prow) * 256 + col] = v;
      }
    }
    sacc += __shfl_xor(sacc, 16);  sacc += __shfl_xor(sacc, 32);
    ssacc += __shfl_xor(ssacc, 16); ssacc += __shfl_xor(ssacc, 32);
    if (quad == 0) {
      atomicAdd(&stats[col], sacc);
      atomicAdd(&stats[256 + col], ssacc);
    }
  }
}

// ---------------- BN2 + relu + transpose to (b, c, n) ----------------
__global__ __launch_bounds__(256) void out_kernel(const float* __restrict__ yraw,
                                                  const float* __restrict__ coef2,
                                                  float* __restrict__ out) {
  __shared__ float t[64][257];
  int tid = threadIdx.x;
  int blk = blockIdx.x;            // 256 = 8 b x 32 n-tiles
  int b = blk >> 5, n0 = (blk & 31) << 6;
  for (int it = 0; it < 64; ++it)
    t[it][tid] = yraw[(b * 2048 + n0 + it) * 256 + tid];
  __syncthreads();
  int nsub = tid & 63, cq = tid >> 6;
  for (int it = 0; it < 64; ++it) {
    int c = (it << 2) + cq;
    float v = coef2[c] * t[nsub][c] + coef2[256 + c];
    out[(b * 256 + c) * 2048 + n0 + nsub] = v > 0.f ? v : 0.f;
  }
}

extern "C" void kernel_launch(void* const* d_in, const int* in_sizes, int n_in,
                              void* d_out, int out_size, void* d_ws, size_t ws_size,
                              hipStream_t stream) {
  const float* x   = (const float*)d_in[0];
  const float* w1  = (const float*)d_in[1];
  const float* g1  = (const float*)d_in[3];
  const float* be1 = (const float*)d_in[4];
  const float* w2  = (const float*)d_in[5];
  const float* g2  = (const float*)d_in[7];
  const float* be2 = (const float*)d_in[8];
  float* out = (float*)d_out;
  char* w = (char*)d_ws;
  // workspace layout (~106.6 MB total)
  float* sqf    = (float*)(w);                 // 16384 * 4 (slot 131072 B)
  int*  idxbuf  = (int*)(w + 131072);          // 327680 * 4     = 1310720
  uint* hu      = (uint*)(w + 1441792);        // h bf16: 83886080 B
  float* xtf    = (float*)(w + 1441792);       // fp32 xT, 8 MB — ALIASES hu
  int*  cbuf    = (int*)(w + 9830400);         // 16384*64*4 = 4 MB — ALIASES hu
                                               // (xtf/cbuf dead before conv1)
  float* yraw   = (float*)(w + 85327872);      // 4194304 * 4    = 16777216
  float* stats  = (float*)(w + 102105088);     // 4 * 256 floats
  float* coef   = (float*)(w + 102109184);     // 4 * 256 floats
  ushort* wp1   = (ushort*)(w + 102113280);    // 196608 * 2 = 393216
  ushort* wpack = (ushort*)(w + 102506496);    // 999424 * 2 = 1998848
  ushort* xbf_t = (ushort*)(w + 104505344);    // 1048576 * 2 -> end 106602496

  hipMemsetAsync(stats, 0, 4096, stream);
  prep_weights<<<4672, 256, 0, stream>>>(w1, w2, wp1, wpack);
  transpose_x<<<256, 256, 0, stream>>>(x, (uint*)xbf_t, xtf, sqf);
  knn_kernel<<<2048, 1024, 0, stream>>>(xbf_t, sqf, cbuf);
  knn_merge<<<4096, 256, 0, stream>>>(xtf, cbuf, idxbuf);
  conv1_mfma<<<1024, 256, 0, stream>>>(xbf_t, idxbuf, wp1, hu, stats);
  finalize_kernel<<<1, 256, 0, stream>>>(stats, g1, be1, coef, 1.f / 163840.f);
  conv2_mfma<<<256, 512, 0, stream>>>(xbf_t, idxbuf, hu, coef, wpack, yraw, stats + 512);
  finalize_kernel<<<1, 256, 0, stream>>>(stats + 512, g2, be2, coef + 512, 1.f / 16384.f);
  out_kernel<<<256, 256, 0, stream>>>(yraw, coef + 512, out);
}

// Round 16
// 379.453 us; speedup vs baseline: 1.3862x; 1.0171x over previous
//
#include <hip/hip_runtime.h>
#include <stdint.h>

typedef unsigned int uint;
typedef unsigned short ushort;
typedef __attribute__((ext_vector_type(8))) short short8;
typedef __attribute__((ext_vector_type(4))) float f32x4;

__device__ __forceinline__ uint f2bf(float f) {
  uint u = __float_as_uint(f);
  return (u + 0x7fffu + ((u >> 16) & 1u)) >> 16;
}
__device__ __forceinline__ float bf2f(uint us) {
  return __uint_as_float(us << 16);
}

// ---------------- weight preprocessing ----------------
// w1: (256, 128, 1, 11)  w2: (256, 128, 1, 40)
// wp1 (bf16), fragment-contiguous: chunk = (t*2+ks)*16 + ctile, t=0..11
//   (t=11 is the U block); element [chunk][lane][8]:
//   c = ctile*16 + (lane&15), d = ks*32 + (lane>>4)*8 + j
//   t<11: val = w1[c][64+d][t];  t==11: val = sum_t(w1[c][d][t]-w1[c][64+d][t])
// wpack (bf16): conv2 GEMM B fragment-contiguous (unchanged from R12):
//   gp = (((kb*2+ks)*16 + ctile)*64 + lane)*8 + j
__global__ __launch_bounds__(256) void prep_weights(
    const float* __restrict__ w1, const float* __restrict__ w2,
    ushort* __restrict__ wp1, ushort* __restrict__ wpack) {
  int g = blockIdx.x * 256 + threadIdx.x;
  if (g < 196608) {
    int chunk = g >> 9;            // (t*2+ks)*16 + ctile
    int r = g & 511;
    int lane = r >> 3, j = r & 7;
    int tks = chunk >> 4;
    int ctile = chunk & 15;
    int t = tks >> 1, ks = tks & 1;
    int c = ctile * 16 + (lane & 15);
    int d = ks * 32 + ((lane >> 4) << 3) + j;
    float val;
    if (t < 11) {
      val = w1[c * 1408 + (64 + d) * 11 + t];
    } else {
      float s = 0.f;
      for (int tt = 0; tt < 11; ++tt)
        s += w1[c * 1408 + d * 11 + tt] - w1[c * 1408 + (64 + d) * 11 + tt];
      val = s;
    }
    wp1[g] = (ushort)f2bf(val);
  } else {
    int gp = g - 196608;            // < 999424 = 61*16384
    int chunk = gp >> 9;            // (kb*2+ks)*16 + ctile
    int r = gp & 511;
    int lane = r >> 3, j = r & 7;
    int kb = chunk >> 5;
    int rem = chunk & 31;
    int ks = rem >> 4, ctile = rem & 15;
    int c = ctile * 16 + (lane & 15);
    int k = kb * 64 + ks * 32 + ((lane >> 4) << 3) + j;
    float val;
    if (k < 64) {
      int d = k;
      float s = 0.f;
      for (int jn = 0; jn < 20; ++jn)
        s += w2[c * 5120 + d * 40 + jn] - w2[c * 5120 + (64 + d) * 40 + jn];
      val = s;
    } else if (k < 1344) {
      int q = k - 64; int jn = q >> 6, d = q & 63;
      val = w2[c * 5120 + (64 + d) * 40 + jn];
    } else {
      int q = k - 1344; int ci = q / 20, jj = q - ci * 20;
      val = w2[c * 5120 + ci * 40 + 20 + jj];
    }
    wpack[gp] = (ushort)f2bf(val);
  }
}

// ---------------- x transpose: bf16 [b][n][d] + fp32 [b][n][d] + sqnorm ----------------
__global__ __launch_bounds__(256) void transpose_x(const float* __restrict__ x,
                                                   uint* __restrict__ xtu,
                                                   float* __restrict__ xtf,
                                                   float* __restrict__ sqf) {
  __shared__ float t[64][65];
  int tid = threadIdx.x;
  int blk = blockIdx.x;            // 256 = 8 b x 32 n-tiles
  int b = blk >> 5, n0 = (blk & 31) << 6;
  const float* xb = x + b * 131072;
  #pragma unroll
  for (int it = 0; it < 16; ++it) {
    int d = (it << 2) + (tid >> 6);
    int n = tid & 63;
    t[d][n] = xb[d * 2048 + n0 + n];
  }
  __syncthreads();
  #pragma unroll
  for (int it = 0; it < 8; ++it) {
    int n = (it << 3) + (tid >> 5);
    int dp = tid & 31;
    float f0 = t[2 * dp][n], f1 = t[2 * dp + 1][n];
    uint v = f2bf(f0) | (f2bf(f1) << 16);
    size_t col = (size_t)(b * 2048 + n0 + n);
    xtu[col * 32 + dp] = v;
    float2 fv; fv.x = f0; fv.y = f1;
    *(float2*)&xtf[(col << 6) + 2 * dp] = fv;
    float s = f0 * f0 + f1 * f1;
    #pragma unroll
    for (int off = 16; off > 0; off >>= 1) s += __shfl_xor(s, off);
    if (dp == 0) sqf[col] = s;
  }
}

// ---------------- kNN v8: column-split halves, 64-KB LDS (2 blocks/CU) ----------------
__global__ __launch_bounds__(1024) void knn_kernel(
    const ushort* __restrict__ xbf_t, const float* __restrict__ sqf,
    int* __restrict__ cbuf) {
  __shared__ uint dist[16][1024];   // 64 KB
  int tid = threadIdx.x;
  int wv = tid >> 6, lane = tid & 63;
  int grp = blockIdx.x >> 1;
  int half = blockIdx.x & 1;
  int cbase = half << 10;
  int row0 = grp << 4;
  int b = row0 >> 11, n0 = row0 & 2047;
  const ushort* xt = xbf_t + ((size_t)b << 17);
  const float* sqb = sqf + (b << 11);
  int m = lane & 15, quad = lane >> 4;
  short8 afr0 = *(const short8*)(xt + ((size_t)(n0 + m) << 6) + quad * 8);
  short8 afr1 = *(const short8*)(xt + ((size_t)(n0 + m) << 6) + 32 + quad * 8);
  for (int t = 0; t < 4; ++t) {
    int lcol = (((wv << 2) + t) << 4) + m;
    int col = cbase + lcol;
    short8 bfr0 = *(const short8*)(xt + ((size_t)col << 6) + quad * 8);
    short8 bfr1 = *(const short8*)(xt + ((size_t)col << 6) + 32 + quad * 8);
    f32x4 c = {};
    c = __builtin_amdgcn_mfma_f32_16x16x32_bf16(afr0, bfr0, c, 0, 0, 0);
    c = __builtin_amdgcn_mfma_f32_16x16x32_bf16(afr1, bfr1, c, 0, 0, 0);
    float sq = sqb[col];
    #pragma unroll
    for (int r = 0; r < 4; ++r) {
      float f = sq - 2.f * c[r];
      uint u = __float_as_uint(f);
      uint srt = u ^ ((uint)((int)u >> 31) | 0x80000000u);
      dist[quad * 4 + r][lcol] = (srt & 0xFFFFF800u) | (uint)col;
    }
  }
  __syncthreads();
  uint* dr = dist[wv];
  int selfl = (n0 + wv) - cbase;
  if (selfl >= 0 && selfl < 1024 && ((selfl & 63) == lane))
    dr[selfl] = 0xFFFFFFFFu;
  uint v0, v1, v2, v3, v4, v5;
  auto scan6 = [&]() {
    v0 = v1 = v2 = v3 = v4 = v5 = 0xFFFFFFFFu;
    #pragma unroll
    for (int l = 0; l < 16; ++l) {
      uint v = dr[(l << 6) + lane];
      uint t0 = v0 > v ? v0 : v;   v0 = v0 < v ? v0 : v;
      uint t1 = v1 > t0 ? v1 : t0; v1 = v1 < t0 ? v1 : t0;
      uint t2 = v2 > t1 ? v2 : t1; v2 = v2 < t1 ? v2 : t1;
      uint t3 = v3 > t2 ? v3 : t2; v3 = v3 < t2 ? v3 : t2;
      uint t4 = v4 > t3 ? v4 : t3; v4 = v4 < t3 ? v4 : t3;
      v5 = v5 < t4 ? v5 : t4;
    }
  };
  scan6();
  int outb = (row0 + wv) * 64 + (half << 5);
  for (int round = 0; round < 16; ++round) {
    uint w0 = v0, w1 = v1;
    #pragma unroll
    for (int off = 32; off > 0; off >>= 1) {
      uint o0 = (uint)__shfl_xor((int)w0, off);
      uint o1 = (uint)__shfl_xor((int)w1, off);
      uint lo = w0 < o0 ? w0 : o0;
      uint hi = w0 < o0 ? o0 : w0;
      uint mn1 = w1 < o1 ? w1 : o1;
      w0 = lo;
      w1 = hi < mn1 ? hi : mn1;
    }
    if (lane == 0) {
      cbuf[outb + 2 * round] = (int)(w0 & 2047u);
      cbuf[outb + 2 * round + 1] = (int)(w1 & 2047u);
    }
    int own0 = ((w0 & 63u) == (uint)lane) ? 1 : 0;
    int own1 = ((w1 & 63u) == (uint)lane) ? 1 : 0;
    if (own0) dr[(w0 & 2047u) & 1023u] = 0xFFFFFFFFu;
    if (own1) dr[(w1 & 2047u) & 1023u] = 0xFFFFFFFFu;
    int cnt = own0 + own1;
    if (cnt == 1) { v0 = v1; v1 = v2; v2 = v3; v3 = v4; v4 = v5; v5 = 0xFFFFFFFFu; }
    else if (cnt == 2) { v0 = v2; v1 = v3; v2 = v4; v3 = v5; v4 = 0xFFFFFFFFu; v5 = 0xFFFFFFFFu; }
    if (v1 == 0xFFFFFFFFu) scan6();
  }
}

// ---------------- kNN merge: fp64 exact re-rank of 64 candidates/row ----------------
__global__ __launch_bounds__(256) void knn_merge(
    const float* __restrict__ xtf, const int* __restrict__ cbuf,
    int* __restrict__ idxout) {
  __shared__ double dkey[4][64];
  __shared__ int ccol[4][64];
  int tid = threadIdx.x;
  int wv = tid >> 6, lane = tid & 63;
  int row = (blockIdx.x << 2) + wv;
  int b = row >> 11, n = row & 2047;
  int ci = cbuf[row * 64 + lane];
  const float* xc = xtf + ((size_t)b << 17);
  const float4* xj4 = (const float4*)(xc + ((size_t)ci << 6));
  const float4* xi4 = (const float4*)(xc + ((size_t)n << 6));
  double dt = 0.0, s2 = 0.0;
  #pragma unroll 4
  for (int d4 = 0; d4 < 16; ++d4) {
    float4 vj = xj4[d4];
    float4 vi = xi4[d4];
    double a0 = (double)vj.x, a1 = (double)vj.y, a2 = (double)vj.z, a3 = (double)vj.w;
    s2 += a0 * a0 + a1 * a1 + a2 * a2 + a3 * a3;
    dt += (double)vi.x * a0 + (double)vi.y * a1 + (double)vi.z * a2 + (double)vi.w * a3;
  }
  dkey[wv][lane] = s2 - 2.0 * dt;
  ccol[wv][lane] = ci;
  __syncthreads();
  double kl = dkey[wv][lane];
  int rank = 0;
  for (int mm = 0; mm < 64; ++mm) {
    double km = dkey[wv][mm];
    int cm = ccol[wv][mm];
    if (km < kl || (km == kl && cm < ci)) ++rank;
  }
  if (rank < 20) idxout[row * 20 + rank] = ci;
}

// ---------------- conv1 as bf16 MFMA v3: slice-outer (each slice read once),
// all B-frags of one ctile register-resident; 4 sequential ctile passes ----------------
// Block: 16 points x 256 channels (4 waves; pass p: ctile = p*4+wave).
__global__ __launch_bounds__(256) void conv1_mfma(
    const ushort* __restrict__ xbf_t, const int* __restrict__ idxbuf,
    const ushort* __restrict__ wp1, uint* __restrict__ hu,
    float* __restrict__ stats) {
  __shared__ ushort sl[21][16][72];   // 48384 B
  __shared__ int nidx[16][20];
  int tid = threadIdx.x;
  int p0 = blockIdx.x << 4;
  int b = p0 >> 11, n0 = p0 & 2047;
  const ushort* xt = xbf_t + ((size_t)b << 17);
  for (int v = tid; v < 320; v += 256) {
    int p = v / 20, j = v - p * 20;
    nidx[p][j] = idxbuf[(p0 + p) * 20 + j];
  }
  __syncthreads();
  for (int v = tid; v < 2688; v += 256) {
    int s = v >> 7;
    int r = v & 127;
    int p = r >> 3, i = r & 7;
    int col = (s == 0) ? (n0 + p) : nidx[p][s - 1];
    *(short8*)&sl[s][p][i << 3] =
        *(const short8*)(xt + ((size_t)col << 6) + (i << 3));
  }
  __syncthreads();
  int lane = tid & 63, wave = tid >> 6;
  int m = lane & 15, quad = lane >> 4;
  #pragma unroll 1
  for (int pass = 0; pass < 4; ++pass) {
    int ctile = (pass << 2) + wave;
    int c = ctile * 16 + m;
    // all B fragments for this ctile: 22 tap-frags + 2 U-frags (contiguous 1KB each)
    short8 tb0[11], tb1[11];
    #pragma unroll
    for (int t = 0; t < 11; ++t) {
      tb0[t] = *(const short8*)(wp1 + (((t * 2 + 0) * 16 + ctile) << 9) + lane * 8);
      tb1[t] = *(const short8*)(wp1 + (((t * 2 + 1) * 16 + ctile) << 9) + lane * 8);
    }
    short8 ub0 = *(const short8*)(wp1 + ((22 * 16 + ctile) << 9) + lane * 8);
    short8 ub1 = *(const short8*)(wp1 + ((23 * 16 + ctile) << 9) + lane * 8);
    f32x4 acc[10] = {};
    f32x4 cacc = {};
    {
      short8 a0 = *(const short8*)&sl[0][m][quad * 8];
      short8 a1 = *(const short8*)&sl[0][m][32 + quad * 8];
      cacc = __builtin_amdgcn_mfma_f32_16x16x32_bf16(a0, ub0, cacc, 0, 0, 0);
      cacc = __builtin_amdgcn_mfma_f32_16x16x32_bf16(a1, ub1, cacc, 0, 0, 0);
    }
    // slice-outer: read each slice once, accumulate into all valid ko = s-1-t
    #pragma unroll
    for (int s = 1; s <= 20; ++s) {
      short8 a0 = *(const short8*)&sl[s][m][quad * 8];
      short8 a1 = *(const short8*)&sl[s][m][32 + quad * 8];
      #pragma unroll
      for (int t = 0; t < 11; ++t) {
        int ko = s - 1 - t;
        if (ko >= 0 && ko < 10) {
          acc[ko] = __builtin_amdgcn_mfma_f32_16x16x32_bf16(a0, tb0[t], acc[ko], 0, 0, 0);
          acc[ko] = __builtin_amdgcn_mfma_f32_16x16x32_bf16(a1, tb1[t], acc[ko], 0, 0, 0);
        }
      }
    }
    // epilogue: D col=lane&15 -> channel, row=quad*4+r -> point; fused stats
    float sacc = 0.f, ssacc = 0.f;
    #pragma unroll
    for (int r = 0; r < 4; ++r) {
      int p = (quad << 2) + r;
      int base5 = ((p0 + p) * 256 + c) * 5;
      float cc = cacc[r];
      #pragma unroll
      for (int q = 0; q < 5; ++q) {
        float f0 = acc[2 * q][r] + cc;
        float f1 = acc[2 * q + 1][r] + cc;
        sacc += f0 + f1;
        ssacc += f0 * f0 + f1 * f1;
        hu[base5 + q] = f2bf(f0) | (f2bf(f1) << 16);
      }
    }
    sacc += __shfl_xor(sacc, 16);  sacc += __shfl_xor(sacc, 32);
    ssacc += __shfl_xor(ssacc, 16); ssacc += __shfl_xor(ssacc, 32);
    if (quad == 0) {
      atomicAdd(&stats[c], sacc);
      atomicAdd(&stats[256 + c], ssacc);
    }
  }
}

__global__ void finalize_kernel(const float* __restrict__ stats,
                                const float* __restrict__ gamma,
                                const float* __restrict__ beta,
                                float* __restrict__ coef, float inv_count) {
  int c = threadIdx.x;
  float m = stats[c] * inv_count;
  float var = stats[256 + c] * inv_count - m * m;
  float a = gamma[c] * rsqrtf(var + 1e-5f);
  coef[c] = a;
  coef[256 + c] = beta[c] - m * a;
}

// ---------------- conv2 as bf16 MFMA GEMM v3 (fused BN2 stats) ----------------
__global__ __launch_bounds__(512) void conv2_mfma(
    const ushort* __restrict__ xbf_t, const int* __restrict__ idxbuf,
    const uint* __restrict__ hu, const float* __restrict__ coef1,
    const ushort* __restrict__ wpack, float* __restrict__ yraw,
    float* __restrict__ stats) {
  __shared__ ushort As[2][4][64][72];   // 73728 B
  __shared__ int nidx[64][20];
  __shared__ float cf[512];
  int tid = threadIdx.x;
  int p0 = blockIdx.x << 6;          // 64 points per block
  int b = p0 >> 11, n0 = p0 & 2047;
  const ushort* xt = xbf_t + ((size_t)b << 17);

  cf[tid] = coef1[tid];
  for (int v = tid; v < 1280; v += 512) {
    int p = v / 20, j = v - p * 20;
    nidx[p][j] = idxbuf[(p0 + p) * 20 + j];
  }
  __syncthreads();

  int pp = tid >> 3;                 // point 0..63
  int off = (tid & 7) << 3;          // 8-col chunk within 64

  auto build = [&](int phase, int buf) {
    int kb0 = phase << 2;
    short8 xv[4];
    uint4 hv[4];
    #pragma unroll
    for (int kc = 0; kc < 4; ++kc) {
      int kb = kb0 + kc;
      if (kb >= 61) continue;
      if (kb < 21) {
        int col = (kb == 0) ? (n0 + pp) : nidx[pp][kb - 1];
        xv[kc] = *(const short8*)(xt + ((size_t)col << 6) + off);
      } else {
        int q0 = (kb - 21) * 64 + off;
        hv[kc] = *(const uint4*)(hu + (size_t)(p0 + pp) * 1280 + (q0 >> 1));
      }
    }
    #pragma unroll
    for (int kc = 0; kc < 4; ++kc) {
      int kb = kb0 + kc;
      if (kb >= 61) continue;
      if (kb < 21) {
        *(short8*)&As[buf][kc][pp][off] = xv[kc];
      } else {
        int q0 = (kb - 21) * 64 + off;
        uint4 hvv = hv[kc];
        float f[8];
        f[0] = bf2f(hvv.x & 0xffffu); f[1] = bf2f(hvv.x >> 16);
        f[2] = bf2f(hvv.y & 0xffffu); f[3] = bf2f(hvv.y >> 16);
        f[4] = bf2f(hvv.z & 0xffffu); f[5] = bf2f(hvv.z >> 16);
        f[6] = bf2f(hvv.w & 0xffffu); f[7] = bf2f(hvv.w >> 16);
        ushort o[8];
        #pragma unroll
        for (int i = 0; i < 8; ++i) {
          int ch = (q0 + i) / 10;
          float vv = f[i] * cf[ch] + cf[256 + ch];
          vv = vv > 0.f ? vv : 0.01f * vv;
          o[i] = (ushort)f2bf(vv);
        }
        *(short8*)&As[buf][kc][pp][off] = *(short8*)o;
      }
    }
  };

  int lane = tid & 63, wave = tid >> 6;
  int m = lane & 15, quad = lane >> 4;
  f32x4 acc[4][2] = {};

  build(0, 0);
  __syncthreads();
  for (int phase = 0; phase < 16; ++phase) {
    int buf = phase & 1;
    if (phase < 15) build(phase + 1, buf ^ 1);
    #pragma unroll
    for (int kc = 0; kc < 4; ++kc) {
      int kb = (phase << 2) + kc;
      if (kb >= 61) break;
      #pragma unroll
      for (int ks = 0; ks < 2; ++ks) {
        short8 afr[4];
        #pragma unroll
        for (int mt = 0; mt < 4; ++mt)
          afr[mt] = *(const short8*)&As[buf][kc][mt * 16 + m][ks * 32 + quad * 8];
        #pragma unroll
        for (int nt = 0; nt < 2; ++nt) {
          const ushort* bp = wpack +
              (((size_t)((kb * 2 + ks) * 16 + (wave << 1) + nt)) << 9) + lane * 8;
          short8 bfr = *(const short8*)bp;
          #pragma unroll
          for (int mt = 0; mt < 4; ++mt)
            acc[mt][nt] = __builtin_amdgcn_mfma_f32_16x16x32_bf16(afr[mt], bfr, acc[mt][nt], 0, 0, 0);
        }
      }
    }
    __syncthreads();
  }
  #pragma unroll
  for (int nt = 0; nt < 2; ++nt) {
    int col = (wave << 5) + nt * 16 + m;
    float sacc = 0.f, ssacc = 0.f;
    #pragma unroll
    for (int mt = 0; mt < 4; ++mt) {
      #pragma unroll
      for (int r = 0; r < 4; ++r) {
        int prow = mt * 16 + quad * 4 + r;
        float v = acc[mt][nt][r];
        sacc += v; ssacc += v * v;
        yraw[(size_t)(p0 + prow) * 256 + col] = v;
      }
    }
    sacc += __shfl_xor(sacc, 16);  sacc += __shfl_xor(sacc, 32);
    ssacc += __shfl_xor(ssacc, 16); ssacc += __shfl_xor(ssacc, 32);
    if (quad == 0) {
      atomicAdd(&stats[col], sacc);
      atomicAdd(&stats[256 + col], ssacc);
    }
  }
}

// ---------------- BN2 + relu + transpose to (b, c, n) ----------------
__global__ __launch_bounds__(256) void out_kernel(const float* __restrict__ yraw,
                                                  const float* __restrict__ coef2,
                                                  float* __restrict__ out) {
  __shared__ float t[64][257];
  int tid = threadIdx.x;
  int blk = blockIdx.x;            // 256 = 8 b x 32 n-tiles
  int b = blk >> 5, n0 = (blk & 31) << 6;
  for (int it = 0; it < 64; ++it)
    t[it][tid] = yraw[(b * 2048 + n0 + it) * 256 + tid];
  __syncthreads();
  int nsub = tid & 63, cq = tid >> 6;
  for (int it = 0; it < 64; ++it) {
    int c = (it << 2) + cq;
    float v = coef2[c] * t[nsub][c] + coef2[256 + c];
    out[(b * 256 + c) * 2048 + n0 + nsub] = v > 0.f ? v : 0.f;
  }
}

extern "C" void kernel_launch(void* const* d_in, const int* in_sizes, int n_in,
                              void* d_out, int out_size, void* d_ws, size_t ws_size,
                              hipStream_t stream) {
  const float* x   = (const float*)d_in[0];
  const float* w1  = (const float*)d_in[1];
  const float* g1  = (const float*)d_in[3];
  const float* be1 = (const float*)d_in[4];
  const float* w2  = (const float*)d_in[5];
  const float* g2  = (const float*)d_in[7];
  const float* be2 = (const float*)d_in[8];
  float* out = (float*)d_out;
  char* w = (char*)d_ws;
  // workspace layout (~106.6 MB total)
  float* sqf    = (float*)(w);                 // 16384 * 4 (slot 131072 B)
  int*  idxbuf  = (int*)(w + 131072);          // 327680 * 4     = 1310720
  uint* hu      = (uint*)(w + 1441792);        // h bf16: 83886080 B
  float* xtf    = (float*)(w + 1441792);       // fp32 xT, 8 MB — ALIASES hu
  int*  cbuf    = (int*)(w + 9830400);         // 16384*64*4 = 4 MB — ALIASES hu
                                               // (xtf/cbuf dead before conv1)
  float* yraw   = (float*)(w + 85327872);      // 4194304 * 4    = 16777216
  float* stats  = (float*)(w + 102105088);     // 4 * 256 floats
  float* coef   = (float*)(w + 102109184);     // 4 * 256 floats
  ushort* wp1   = (ushort*)(w + 102113280);    // 196608 * 2 = 393216
  ushort* wpack = (ushort*)(w + 102506496);    // 999424 * 2 = 1998848
  ushort* xbf_t = (ushort*)(w + 104505344);    // 1048576 * 2 -> end 106602496

  hipMemsetAsync(stats, 0, 4096, stream);
  prep_weights<<<4672, 256, 0, stream>>>(w1, w2, wp1, wpack);
  transpose_x<<<256, 256, 0, stream>>>(x, (uint*)xbf_t, xtf, sqf);
  knn_kernel<<<2048, 1024, 0, stream>>>(xbf_t, sqf, cbuf);
  knn_merge<<<4096, 256, 0, stream>>>(xtf, cbuf, idxbuf);
  conv1_mfma<<<1024, 256, 0, stream>>>(xbf_t, idxbuf, wp1, hu, stats);
  finalize_kernel<<<1, 256, 0, stream>>>(stats, g1, be1, coef, 1.f / 163840.f);
  conv2_mfma<<<256, 512, 0, stream>>>(xbf_t, idxbuf, hu, coef, wpack, yraw, stats + 512);
  finalize_kernel<<<1, 256, 0, stream>>>(stats + 512, g2, be2, coef + 512, 1.f / 16384.f);
  out_kernel<<<256, 256, 0, stream>>>(yraw, coef + 512, out);
}